// Round 8
// baseline (66.013 us; speedup 1.0000x reference)
//
#include <hip/hip_runtime.h>

// GroupWiseAgg: MVS group-wise correlation cost volume.
// features: (NVIEW=4, C=32, H=112, W=144) fp32
// proj:     (NVIEW, 2, 4, 4) fp32  [0]=extrinsic E, [1]=intrinsic K
// depth:    (D=48, H=112, W=144) fp32
// out:      (G=8, D, H, W) fp32
//
// R8: LDS strip staging. Block = 48 same-row pixels x 12 depths.
// Per view: block-reduce the clamped tap bounding box, stage the fp16 HWC
// strip into LDS once (coalesced), serve all 2304 tap reads from LDS
// (padded 5x16B/pixel stride for bank spread). Coords precomputed as 4B
// fixed-point 8.8 records (XCD-banded). Per-view fallback to direct global
// taps if the strip exceeds the LDS budget.

typedef _Float16 h2  __attribute__((ext_vector_type(2)));
typedef _Float16 h8v __attribute__((ext_vector_type(8)));
struct __attribute__((aligned(16))) h2x4 { h2 x, y, z, w; };

constexpr int NVIEW = 4;
constexpr int C     = 32;
constexpr int D     = 48;
constexpr int H     = 112;
constexpr int W     = 144;
constexpr int HW    = H * W;        // 16128
constexpr int TOTAL = D * HW;       // 774144
constexpr int NXCD  = 8;
constexpr int BAND  = HW / NXCD;    // 2016

// staged-main geometry
constexpr int P_CHUNK = 48;                    // pixels/block, divides W
constexpr int NCHUNK  = HW / P_CHUNK;          // 336
constexpr int DSEG    = 12;                    // depths/block
constexpr int NSEG    = D / DSEG;              // 4
constexpr int STAGED_BLOCKS = NCHUNK * NSEG;   // 1344
constexpr int CHUNK_PER_XCD = NCHUNK / NXCD;   // 42
constexpr int MAXPIX  = 480;                   // strip pixel budget
constexpr int PADU    = 5;                     // 16B units per pixel (4 + 1 pad)

// legacy mid-tier geometry
constexpr int DCHUNK = 4;
constexpr int NDC    = D / DCHUNK;
constexpr int WPB    = 64;
constexpr int MID_BLOCKS = NXCD * ((BAND * NDC) / WPB);  // 3024

// prep kernel grid
constexpr int COORD_BLOCKS = 3 * TOTAL / 256;  // 9072 (divides exactly)
constexpr int TRANS_BLOCKS = NVIEW * HW / 256; // 252
constexpr int PREP_BLOCKS  = COORD_BLOCKS + TRANS_BLOCKS;

// ws layout
constexpr size_t FEAH_BYTES = (size_t)NVIEW * HW * C * 2;   // 4,128,768
constexpr size_t RT_OFF     = FEAH_BYTES;
constexpr size_t CC_OFF     = RT_OFF + 256;
constexpr size_t CC_BYTES   = (size_t)3 * TOTAL * 4;        // 9.29 MB
constexpr size_t WS_NEED    = CC_OFF + CC_BYTES;

#if __has_builtin(__builtin_amdgcn_fdot2)
__device__ inline float dot2f(h2 a, h2 b, float c) {
    return __builtin_amdgcn_fdot2(a, b, c, false);
}
#else
__device__ inline float dot2f(h2 a, h2 b, float c) {
    return fmaf((float)a.x, (float)b.x, fmaf((float)a.y, (float)b.y, c));
}
#endif

__device__ inline h2 as_h2(float f) { union { float f; h2 h; } u; u.f = f; return u.h; }

__device__ inline int wave_min_i(int v) {
    #pragma unroll
    for (int m = 1; m < 64; m <<= 1) v = min(v, __shfl_xor(v, m));
    return v;
}
__device__ inline int wave_max_i(int v) {
    #pragma unroll
    for (int m = 1; m < 64; m <<= 1) v = max(v, __shfl_xor(v, m));
    return v;
}

// ---------- matrix helpers ----------
__device__ inline void fold_mat(const float* pm, double out[16]) {
    const float* E = pm;
    const float* K = pm + 16;
    for (int i = 0; i < 3; ++i)
        for (int j = 0; j < 4; ++j) {
            double s = 0.0;
            for (int k = 0; k < 3; ++k) s += (double)K[i*4+k] * (double)E[k*4+j];
            out[i*4+j] = s;
        }
    for (int j = 0; j < 4; ++j) out[12+j] = (double)E[12+j];
}

__device__ inline void inv4(const double A[16], double out[16]) {
    double M[4][8];
    for (int r = 0; r < 4; ++r) {
        for (int c = 0; c < 4; ++c) M[r][c] = A[r*4+c];
        for (int c = 0; c < 4; ++c) M[r][4+c] = (r == c) ? 1.0 : 0.0;
    }
    for (int col = 0; col < 4; ++col) {
        int piv = col;
        double best = fabs(M[col][col]);
        for (int r = col+1; r < 4; ++r) {
            double v = fabs(M[r][col]);
            if (v > best) { best = v; piv = r; }
        }
        if (piv != col)
            for (int c = 0; c < 8; ++c) { double t = M[col][c]; M[col][c] = M[piv][c]; M[piv][c] = t; }
        double ip = 1.0 / M[col][col];
        for (int c = 0; c < 8; ++c) M[col][c] *= ip;
        for (int r = 0; r < 4; ++r) {
            if (r == col) continue;
            double f = M[r][col];
            if (f != 0.0)
                for (int c = 0; c < 8; ++c) M[r][c] -= f * M[col][c];
        }
    }
    for (int r = 0; r < 4; ++r)
        for (int c = 0; c < 4; ++c) out[r*4+c] = M[r][4+c];
}

__device__ inline void compute_rt(const float* proj, float* dst) {
    double Pref[16], Pinv[16];
    fold_mat(proj, Pref);
    inv4(Pref, Pinv);
    for (int v = 1; v < NVIEW; ++v) {
        double Ps[16], Pr[16];
        fold_mat(proj + v*32, Ps);
        for (int i = 0; i < 4; ++i)
            for (int j = 0; j < 4; ++j) {
                double s = 0.0;
                for (int k = 0; k < 4; ++k) s += Ps[i*4+k] * Pinv[k*4+j];
                Pr[i*4+j] = s;
            }
        float* o = dst + (v-1)*12;
        for (int i = 0; i < 3; ++i)
            for (int j = 0; j < 3; ++j) o[i*3+j] = (float)Pr[i*4+j];
        for (int i = 0; i < 3; ++i) o[9+i] = (float)Pr[i*4+3];
    }
}

// ---------- kernel 0: rt once ----------
__global__ void rt_kernel(const float* __restrict__ proj, float* __restrict__ rtbuf) {
    if (threadIdx.x == 0) compute_rt(proj, rtbuf);
}

// ---------- kernel 1: fused coords (4B fixed-point) + transpose ----------
__global__ __launch_bounds__(256) void prep_kernel(
    const float* __restrict__ fea,     // (NVIEW, C, HW) fp32
    const float* __restrict__ depth,   // (D, HW)
    const float* __restrict__ rtbuf,   // 36 floats
    _Float16* __restrict__ feaH,       // (NVIEW, HW, C) fp16
    uint* __restrict__ planeC)         // (3, TOTAL) packed {pxq16, pyq16}
{
    const int b = blockIdx.x;
    if (b < COORD_BLOCKS) {
        // XCD-banded coords: xcd owns pixels [xcd*BAND, (xcd+1)*BAND)
        const int xcd  = b % NXCD;
        const int rest = b / NXCD;          // 0..1133
        const int v    = rest / 378;        // 0..2
        const int j    = rest % 378;
        const int local = j * 256 + threadIdx.x;   // 0..96767 = BAND*D
        const int ploc  = local % BAND;
        const int d     = local / BAND;
        const int p     = xcd * BAND + ploc;
        const int pd    = d * HW + p;

        const float* rt = rtbuf + v*12;
        const float fx = (float)(p % W);
        const float fy = (float)(p / W);
        const float dep = depth[pd];

        const float X = fmaf(fmaf(rt[0], fx, fmaf(rt[1], fy, rt[2])), dep, rt[9]);
        const float Y = fmaf(fmaf(rt[3], fx, fmaf(rt[4], fy, rt[5])), dep, rt[10]);
        const float Z = fmaf(fmaf(rt[6], fx, fmaf(rt[7], fy, rt[8])), dep, rt[11]);
        const float iZ = __builtin_amdgcn_rcpf(Z);
        const float px = X * iZ;
        const float py = Y * iZ;

        // fixed-point 8.8 with +8 offset; NaN/inf collapse to clamped ends
        const float vx = fminf(fmaxf((px + 8.f) * 256.f, 0.f), 65535.f);
        const float vy = fminf(fmaxf((py + 8.f) * 256.f, 0.f), 65535.f);
        const uint pxq = (uint)vx;
        const uint pyq = (uint)vy;
        planeC[(size_t)v * TOTAL + pd] = pxq | (pyq << 16);
    } else {
        // transpose CHW fp32 -> HWC fp16
        const int t = (b - COORD_BLOCKS) * 256 + threadIdx.x;  // v*HW + p
        const int v = t / HW;
        const int p = t - v * HW;
        const float* src = fea + (size_t)v*C*HW + p;
        h8v ov[4];
        #pragma unroll
        for (int q = 0; q < 4; ++q) {
            #pragma unroll
            for (int k = 0; k < 8; ++k) ov[q][k] = (_Float16)src[(q*8+k)*HW];
        }
        h8v* dst = (h8v*)(feaH + (size_t)t * C);
        #pragma unroll
        for (int q = 0; q < 4; ++q) dst[q] = ov[q];
    }
}

// ---------- kernel 2: staged main ----------
__global__ __launch_bounds__(192) void gwc_staged(
    const _Float16* __restrict__ feaH,   // (NVIEW, HW, C) fp16
    const uint* __restrict__ planeC,     // (3, TOTAL)
    float* __restrict__ out)             // (G=8, D, HW)
{
    __shared__ int sb[4];
    __shared__ __align__(16) ushort strip[MAXPIX * PADU * 8];  // 38,400 B

    const int b    = blockIdx.x;
    const int xcd  = b % NXCD;
    const int i    = b / NXCD;                        // 0..167
    const int chunk = xcd * CHUNK_PER_XCD + (i >> 2); // same-row 48-px chunk
    const int dseg  = i & 3;
    const int tid  = threadIdx.x;
    const int cl   = tid >> 2;          // 0..47  (pixel within chunk)
    const int l    = tid & 3;           // channel octet: groups 2l, 2l+1
    const int p    = chunk * P_CHUNK + cl;

    // ref features octet
    h2 refq[4];
    {
        const h2* rp = (const h2*)(feaH + (size_t)p*C + l*8);
        refq[0] = rp[0]; refq[1] = rp[1]; refq[2] = rp[2]; refq[3] = rp[3];
    }

    float accA[DSEG], accB[DSEG];
    #pragma unroll
    for (int dd = 0; dd < DSEG; ++dd) { accA[dd] = 0.f; accB[dd] = 0.f; }

    for (int v = 0; v < 3; ++v) {
        // load this pixel's 12 coord records for view v
        uint rec[DSEG];
        const uint* pc = planeC + (size_t)v * TOTAL + (size_t)(dseg * DSEG) * HW + p;
        #pragma unroll
        for (int dd = 0; dd < DSEG; ++dd) rec[dd] = pc[dd * HW];

        // local clamped bounding box
        int mnx = 1000, mxx = -1, mny = 1000, mxy = -1;
        #pragma unroll
        for (int dd = 0; dd < DSEG; ++dd) {
            const int xi = rec[dd] & 0xffffu, yi = rec[dd] >> 16;
            const int x0 = (xi >> 8) - 8,   y0 = (yi >> 8) - 8;
            const int xc0 = min(max(x0, 0), W-1), xc1 = min(max(x0+1, 0), W-1);
            const int yc0 = min(max(y0, 0), H-1), yc1 = min(max(y0+1, 0), H-1);
            mnx = min(mnx, xc0); mxx = max(mxx, xc1);
            mny = min(mny, yc0); mxy = max(mxy, yc1);
        }
        mnx = wave_min_i(mnx); mxx = wave_max_i(mxx);
        mny = wave_min_i(mny); mxy = wave_max_i(mxy);

        __syncthreads();   // previous view's strip no longer read; sb reusable
        if (tid == 0) { sb[0] = 1000; sb[1] = -1; sb[2] = 1000; sb[3] = -1; }
        __syncthreads();
        if ((tid & 63) == 0) {
            atomicMin(&sb[0], mnx); atomicMax(&sb[1], mxx);
            atomicMin(&sb[2], mny); atomicMax(&sb[3], mxy);
        }
        __syncthreads();
        const int xmin = sb[0], xmax = sb[1], ymin = sb[2], ymax = sb[3];
        const int SW = xmax - xmin + 1;
        const int SH = ymax - ymin + 1;

        if (SW * SH <= MAXPIX) {
            // ---- stage strip (coalesced) ----
            for (int ry = 0; ry < SH; ++ry) {
                const _Float16* srow = feaH + ((size_t)(v+1)*HW + (size_t)(ymin+ry)*W + xmin) * C;
                ushort* dbase = strip + (size_t)ry * SW * (PADU*8);
                for (int u = tid; u < SW*4; u += 192) {
                    const int rx = u >> 2, q = u & 3;
                    *(float4*)(dbase + ((size_t)rx*PADU + q)*8) =
                        *(const float4*)(srow + (size_t)rx*C + q*8);
                }
            }
            __syncthreads();

            // ---- consume from LDS ----
            #pragma unroll
            for (int dd = 0; dd < DSEG; ++dd) {
                const int xi = rec[dd] & 0xffffu, yi = rec[dd] >> 16;
                const int x0 = (xi >> 8) - 8,   y0 = (yi >> 8) - 8;
                const float dxf = (float)(xi & 255) * (1.f/256.f);
                const float dyf = (float)(yi & 255) * (1.f/256.f);
                float w00 = (1.f-dxf)*(1.f-dyf), w10 = dxf*(1.f-dyf);
                float w01 = (1.f-dxf)*dyf,       w11 = dxf*dyf;
                const bool vx0 = (x0 >= 0) & (x0 < W);
                const bool vx1 = (x0 >= -1) & (x0 < W-1);
                const bool vy0 = (y0 >= 0) & (y0 < H);
                const bool vy1 = (y0 >= -1) & (y0 < H-1);
                if (!(vx0 && vy0)) w00 = 0.f;
                if (!(vx1 && vy0)) w10 = 0.f;
                if (!(vx0 && vy1)) w01 = 0.f;
                if (!(vx1 && vy1)) w11 = 0.f;
                const int lx0 = min(max(x0,   0), W-1) - xmin;
                const int lx1 = min(max(x0+1, 0), W-1) - xmin;
                const int ly0 = min(max(y0,   0), H-1) - ymin;
                const int ly1 = min(max(y0+1, 0), H-1) - ymin;

                const h2x4 t00 = *(const h2x4*)(strip + (((size_t)(ly0*SW+lx0))*PADU + l)*8);
                const h2x4 t10 = *(const h2x4*)(strip + (((size_t)(ly0*SW+lx1))*PADU + l)*8);
                const h2x4 t01 = *(const h2x4*)(strip + (((size_t)(ly1*SW+lx0))*PADU + l)*8);
                const h2x4 t11 = *(const h2x4*)(strip + (((size_t)(ly1*SW+lx1))*PADU + l)*8);

                h2 w00s; w00s.x = (_Float16)w00; w00s.y = w00s.x;
                h2 w10s; w10s.x = (_Float16)w10; w10s.y = w10s.x;
                h2 w01s; w01s.x = (_Float16)w01; w01s.y = w01s.x;
                h2 w11s; w11s.x = (_Float16)w11; w11s.y = w11s.x;

                h2 s0 = w00s*t00.x + w10s*t10.x + w01s*t01.x + w11s*t11.x;
                h2 s1 = w00s*t00.y + w10s*t10.y + w01s*t01.y + w11s*t11.y;
                h2 s2 = w00s*t00.z + w10s*t10.z + w01s*t01.z + w11s*t11.z;
                h2 s3 = w00s*t00.w + w10s*t10.w + w01s*t01.w + w11s*t11.w;

                accA[dd] = dot2f(s0, refq[0], accA[dd]);
                accA[dd] = dot2f(s1, refq[1], accA[dd]);
                accB[dd] = dot2f(s2, refq[2], accB[dd]);
                accB[dd] = dot2f(s3, refq[3], accB[dd]);
            }
        } else {
            // ---- fallback: direct global taps ----
            #pragma unroll
            for (int dd = 0; dd < DSEG; ++dd) {
                const int xi = rec[dd] & 0xffffu, yi = rec[dd] >> 16;
                const int x0 = (xi >> 8) - 8,   y0 = (yi >> 8) - 8;
                const float dxf = (float)(xi & 255) * (1.f/256.f);
                const float dyf = (float)(yi & 255) * (1.f/256.f);
                float w00 = (1.f-dxf)*(1.f-dyf), w10 = dxf*(1.f-dyf);
                float w01 = (1.f-dxf)*dyf,       w11 = dxf*dyf;
                const bool vx0 = (x0 >= 0) & (x0 < W);
                const bool vx1 = (x0 >= -1) & (x0 < W-1);
                const bool vy0 = (y0 >= 0) & (y0 < H);
                const bool vy1 = (y0 >= -1) & (y0 < H-1);
                if (!(vx0 && vy0)) w00 = 0.f;
                if (!(vx1 && vy0)) w10 = 0.f;
                if (!(vx0 && vy1)) w01 = 0.f;
                if (!(vx1 && vy1)) w11 = 0.f;
                const int xc0 = min(max(x0,0),W-1), xc1 = min(max(x0+1,0),W-1);
                const int yc0 = min(max(y0,0),H-1), yc1 = min(max(y0+1,0),H-1);
                const int r0 = yc0*W, r1 = yc1*W;
                const _Float16* bv = feaH + (size_t)(v+1)*HW*C + l*8;
                const h2x4 t00 = *(const h2x4*)(bv + (size_t)(r0+xc0)*C);
                const h2x4 t10 = *(const h2x4*)(bv + (size_t)(r0+xc1)*C);
                const h2x4 t01 = *(const h2x4*)(bv + (size_t)(r1+xc0)*C);
                const h2x4 t11 = *(const h2x4*)(bv + (size_t)(r1+xc1)*C);
                h2 w00s; w00s.x = (_Float16)w00; w00s.y = w00s.x;
                h2 w10s; w10s.x = (_Float16)w10; w10s.y = w10s.x;
                h2 w01s; w01s.x = (_Float16)w01; w01s.y = w01s.x;
                h2 w11s; w11s.x = (_Float16)w11; w11s.y = w11s.x;
                h2 s0 = w00s*t00.x + w10s*t10.x + w01s*t01.x + w11s*t11.x;
                h2 s1 = w00s*t00.y + w10s*t10.y + w01s*t01.y + w11s*t11.y;
                h2 s2 = w00s*t00.z + w10s*t10.z + w01s*t01.z + w11s*t11.z;
                h2 s3 = w00s*t00.w + w10s*t10.w + w01s*t01.w + w11s*t11.w;
                accA[dd] = dot2f(s0, refq[0], accA[dd]);
                accA[dd] = dot2f(s1, refq[1], accA[dd]);
                accB[dd] = dot2f(s2, refq[2], accB[dd]);
                accB[dd] = dot2f(s3, refq[3], accB[dd]);
            }
        }
    }

    const float scale = 1.f / 12.f;
    #pragma unroll
    for (int dd = 0; dd < DSEG; ++dd) {
        const int didx = (dseg * DSEG + dd) * HW + p;
        __builtin_nontemporal_store(accA[dd] * scale, &out[(2*l  )*TOTAL + didx]);
        __builtin_nontemporal_store(accB[dd] * scale, &out[(2*l+1)*TOTAL + didx]);
    }
}

// ---------- mid tier (R5-style, needs only feaH) ----------
__global__ __launch_bounds__(256) void gwc_mid(
    const _Float16* __restrict__ feaH,
    const float* __restrict__ proj,
    const float* __restrict__ depth,
    float* __restrict__ out)
{
    __shared__ float s_rt[(NVIEW-1)*12];
    if (threadIdx.x == 0) compute_rt(proj, s_rt);
    __syncthreads();

    const int b    = blockIdx.x;
    const int xcd  = b % NXCD;
    const int j    = b / NXCD;
    const int wloc = j * WPB + (threadIdx.x >> 2);
    const int l    = threadIdx.x & 3;
    const int ploc = wloc % BAND;
    const int dc   = wloc / BAND;
    const int p    = xcd * BAND + ploc;

    const float fx = (float)(p % W);
    const float fy = (float)(p / W);

    h2 refq[4];
    {
        const h2* rp = (const h2*)(feaH + (size_t)p*C + l*8);
        refq[0] = rp[0]; refq[1] = rp[1]; refq[2] = rp[2]; refq[3] = rp[3];
    }

    float rx[3], ry[3], rz[3], tx[3], ty[3], tz[3];
    #pragma unroll
    for (int v = 0; v < 3; ++v) {
        const float* rt = s_rt + v*12;
        rx[v] = fmaf(rt[0], fx, fmaf(rt[1], fy, rt[2]));
        ry[v] = fmaf(rt[3], fx, fmaf(rt[4], fy, rt[5]));
        rz[v] = fmaf(rt[6], fx, fmaf(rt[7], fy, rt[8]));
        tx[v] = rt[9]; ty[v] = rt[10]; tz[v] = rt[11];
    }

    const float scale = 1.f / 12.f;
    for (int dd = 0; dd < DCHUNK; ++dd) {
        const int didx = (dc*DCHUNK + dd)*HW + p;
        const float dep = depth[didx];
        float accA = 0.f, accB = 0.f;
        #pragma unroll
        for (int v = 0; v < 3; ++v) {
            const float X = fmaf(rx[v], dep, tx[v]);
            const float Y = fmaf(ry[v], dep, ty[v]);
            const float Z = fmaf(rz[v], dep, tz[v]);
            const float iZ = __builtin_amdgcn_rcpf(Z);
            const float px = X * iZ, py = Y * iZ;
            const float x0f = floorf(px), y0f = floorf(py);
            const float dx = px - x0f, dy = py - y0f;
            const int x0 = (int)x0f, y0 = (int)y0f;
            const int x1 = x0 + 1,  y1 = y0 + 1;
            float w00 = (1.f-dx)*(1.f-dy), w10 = dx*(1.f-dy);
            float w01 = (1.f-dx)*dy,       w11 = dx*dy;
            const bool vx0 = (x0 >= 0) & (x0 < W), vx1 = (x1 >= 0) & (x1 < W);
            const bool vy0 = (y0 >= 0) & (y0 < H), vy1 = (y1 >= 0) & (y1 < H);
            if (!(vx0 && vy0)) w00 = 0.f;
            if (!(vx1 && vy0)) w10 = 0.f;
            if (!(vx0 && vy1)) w01 = 0.f;
            if (!(vx1 && vy1)) w11 = 0.f;
            const int xc0 = min(max(x0,0),W-1), xc1 = min(max(x1,0),W-1);
            const int yc0 = min(max(y0,0),H-1), yc1 = min(max(y1,0),H-1);
            const int r0 = yc0*W, r1 = yc1*W;
            const _Float16* bv = feaH + (size_t)(v+1)*HW*C + l*8;
            const h2x4 t00 = *(const h2x4*)(bv + (size_t)(r0+xc0)*C);
            const h2x4 t10 = *(const h2x4*)(bv + (size_t)(r0+xc1)*C);
            const h2x4 t01 = *(const h2x4*)(bv + (size_t)(r1+xc0)*C);
            const h2x4 t11 = *(const h2x4*)(bv + (size_t)(r1+xc1)*C);
            h2 w00s; w00s.x=(_Float16)w00; w00s.y=w00s.x;
            h2 w10s; w10s.x=(_Float16)w10; w10s.y=w10s.x;
            h2 w01s; w01s.x=(_Float16)w01; w01s.y=w01s.x;
            h2 w11s; w11s.x=(_Float16)w11; w11s.y=w11s.x;
            h2 s0 = w00s*t00.x + w10s*t10.x + w01s*t01.x + w11s*t11.x;
            h2 s1 = w00s*t00.y + w10s*t10.y + w01s*t01.y + w11s*t11.y;
            h2 s2 = w00s*t00.z + w10s*t10.z + w01s*t01.z + w11s*t11.z;
            h2 s3 = w00s*t00.w + w10s*t10.w + w01s*t01.w + w11s*t11.w;
            accA = dot2f(s0, refq[0], accA);
            accA = dot2f(s1, refq[1], accA);
            accB = dot2f(s2, refq[2], accB);
            accB = dot2f(s3, refq[3], accB);
        }
        __builtin_nontemporal_store(accA * scale, &out[(2*l  )*TOTAL + didx]);
        __builtin_nontemporal_store(accB * scale, &out[(2*l+1)*TOTAL + didx]);
    }
}

// ---------- last-resort fallback ----------
__global__ __launch_bounds__(256) void gwc_fallback(
    const float* __restrict__ fea,
    const float* __restrict__ proj,
    const float* __restrict__ depth,
    float* __restrict__ out)
{
    __shared__ float s_rt[(NVIEW-1)*12];
    if (threadIdx.x == 0) compute_rt(proj, s_rt);
    __syncthreads();

    const int tid = blockIdx.x * blockDim.x + threadIdx.x;
    const int p   = tid % HW;
    const float dep = depth[tid];
    const float fx = (float)(p % W);
    const float fy = (float)(p / W);

    float refv[C];
    #pragma unroll
    for (int c = 0; c < C; ++c) refv[c] = fea[c*HW + p];

    float acc[8];
    #pragma unroll
    for (int g = 0; g < 8; ++g) acc[g] = 0.f;

    #pragma unroll
    for (int v = 1; v < NVIEW; ++v) {
        const float* rt = s_rt + (v-1)*12;
        const float X = fmaf(fmaf(rt[0], fx, fmaf(rt[1], fy, rt[2])), dep, rt[9]);
        const float Y = fmaf(fmaf(rt[3], fx, fmaf(rt[4], fy, rt[5])), dep, rt[10]);
        const float Z = fmaf(fmaf(rt[6], fx, fmaf(rt[7], fy, rt[8])), dep, rt[11]);
        const float px = X / Z, py = Y / Z;
        const float x0f = floorf(px), y0f = floorf(py);
        const float dx = px - x0f, dy = py - y0f;
        const int x0 = (int)x0f, y0 = (int)y0f;
        const int x1 = x0 + 1,  y1 = y0 + 1;
        float w00 = (1.f-dx)*(1.f-dy), w10 = dx*(1.f-dy), w01 = (1.f-dx)*dy, w11 = dx*dy;
        const bool vx0 = (x0 >= 0) & (x0 < W), vx1 = (x1 >= 0) & (x1 < W);
        const bool vy0 = (y0 >= 0) & (y0 < H), vy1 = (y1 >= 0) & (y1 < H);
        if (!(vx0 && vy0)) w00 = 0.f;
        if (!(vx1 && vy0)) w10 = 0.f;
        if (!(vx0 && vy1)) w01 = 0.f;
        if (!(vx1 && vy1)) w11 = 0.f;
        const int xc0 = min(max(x0, 0), W-1), xc1 = min(max(x1, 0), W-1);
        const int yc0 = min(max(y0, 0), H-1), yc1 = min(max(y1, 0), H-1);
        const int o00 = yc0*W + xc0, o10 = yc0*W + xc1;
        const int o01 = yc1*W + xc0, o11 = yc1*W + xc1;
        const float* Fv = fea + v*(C*HW);
        #pragma unroll
        for (int c = 0; c < C; ++c) {
            const float* Fc = Fv + c*HW;
            const float s = w00*Fc[o00] + w10*Fc[o10] + w01*Fc[o01] + w11*Fc[o11];
            acc[c >> 2] = fmaf(s, refv[c], acc[c >> 2]);
        }
    }
    const float scale = 1.f / 12.f;
    #pragma unroll
    for (int g = 0; g < 8; ++g)
        out[g*TOTAL + tid] = acc[g] * scale;
}

extern "C" void kernel_launch(void* const* d_in, const int* in_sizes, int n_in,
                              void* d_out, int out_size, void* d_ws, size_t ws_size,
                              hipStream_t stream) {
    const float* fea   = (const float*)d_in[0];
    const float* proj  = (const float*)d_in[1];
    const float* depth = (const float*)d_in[2];
    float* out = (float*)d_out;
    char* ws = (char*)d_ws;

    if (ws_size >= WS_NEED) {
        _Float16* feaH = (_Float16*)ws;
        float*    rtb  = (float*)(ws + RT_OFF);
        uint*     pC   = (uint*)(ws + CC_OFF);
        rt_kernel<<<1, 64, 0, stream>>>(proj, rtb);
        prep_kernel<<<PREP_BLOCKS, 256, 0, stream>>>(fea, depth, rtb, feaH, pC);
        gwc_staged<<<STAGED_BLOCKS, 192, 0, stream>>>(feaH, pC, out);
    } else if (ws_size >= FEAH_BYTES) {
        _Float16* feaH = (_Float16*)ws;
        // reuse prep's transpose path only via mid tier's own transpose
        // (prep needs planeC space) -> do transpose with a dedicated launch
        // of prep's transpose blocks is not possible; use mid tier directly.
        // Simple: transpose via prep-style loop in gwc_mid is absent, so
        // fall back to monolithic if we cannot fit coords.
        gwc_fallback<<<TOTAL/256, 256, 0, stream>>>(fea, proj, depth, out);
    } else {
        gwc_fallback<<<TOTAL/256, 256, 0, stream>>>(fea, proj, depth, out);
    }
}

// Round 9
// 47.462 us; speedup vs baseline: 1.3909x; 1.3909x over previous
//
#include <hip/hip_runtime.h>

// GroupWiseAgg: MVS group-wise correlation cost volume.
// features: (NVIEW=4, C=32, H=112, W=144) fp32
// proj:     (NVIEW, 2, 4, 4) fp32  [0]=extrinsic E, [1]=intrinsic K
// depth:    (D=48, H=112, W=144) fp32
// out:      (G=8, D, H, W) fp32
//
// R9 = R7 structure (proven best), minus overheads:
//   rt_kernel: fold + fp64 inverse -> rt[36] (1 tiny launch)
//   prep_kernel: FUSED coords + transpose. Coords store PRE-CLAMPED packed
//     tap indices {xc0,xc1,yc0,yc1} (4B) + 4 fp16 weights with validity
//     zeros baked (8B) -> main kernel does no clamping.
//   gwc_main: 4 lanes/pixel x 4 depths; preload 12 records; 12 tap gathers
//     per depth; packed fp16 blend + fdot2. launch_bounds(256,5).

typedef _Float16 h2  __attribute__((ext_vector_type(2)));
typedef _Float16 h8v __attribute__((ext_vector_type(8)));
struct __attribute__((aligned(16))) h2x4 { h2 x, y, z, w; };

constexpr int NVIEW = 4;
constexpr int C     = 32;
constexpr int D     = 48;
constexpr int H     = 112;
constexpr int W     = 144;
constexpr int HW    = H * W;        // 16128
constexpr int TOTAL = D * HW;       // 774144
constexpr int DCHUNK = 4;
constexpr int NDC    = D / DCHUNK;  // 12
constexpr int NXCD   = 8;
constexpr int BAND   = HW / NXCD;   // 2016
constexpr int WPB    = 64;
constexpr int MAIN_BLOCKS = NXCD * ((BAND * NDC) / WPB);  // 3024

// prep grid
constexpr int COORD_BLOCKS = 3 * TOTAL / 256;  // 9072
constexpr int TRANS_BLOCKS = NVIEW * HW / 256; // 252
constexpr int PREP_BLOCKS  = COORD_BLOCKS + TRANS_BLOCKS;

// ws layout
constexpr size_t FEAH_BYTES = (size_t)NVIEW * HW * C * 2;   // 4,128,768
constexpr size_t RT_OFF     = FEAH_BYTES;
constexpr size_t CA_OFF     = RT_OFF + 256;
constexpr size_t CA_BYTES   = (size_t)3 * TOTAL * 8;        // packed idx + wA
constexpr size_t CB_OFF     = CA_OFF + CA_BYTES;
constexpr size_t CB_BYTES   = (size_t)3 * TOTAL * 4;        // wB
constexpr size_t WS_NEED    = CB_OFF + CB_BYTES;

#if __has_builtin(__builtin_amdgcn_fdot2)
__device__ inline float dot2f(h2 a, h2 b, float c) {
    return __builtin_amdgcn_fdot2(a, b, c, false);
}
#else
__device__ inline float dot2f(h2 a, h2 b, float c) {
    return fmaf((float)a.x, (float)b.x, fmaf((float)a.y, (float)b.y, c));
}
#endif

__device__ inline h2 u2h(uint v)  { union { uint u; h2 h; } x; x.u = v; return x.h; }
__device__ inline uint h2u(h2 v)  { union { uint u; h2 h; } x; x.h = v; return x.u; }

// ---------- matrix helpers ----------
__device__ inline void fold_mat(const float* pm, double out[16]) {
    const float* E = pm;
    const float* K = pm + 16;
    for (int i = 0; i < 3; ++i)
        for (int j = 0; j < 4; ++j) {
            double s = 0.0;
            for (int k = 0; k < 3; ++k) s += (double)K[i*4+k] * (double)E[k*4+j];
            out[i*4+j] = s;
        }
    for (int j = 0; j < 4; ++j) out[12+j] = (double)E[12+j];
}

__device__ inline void inv4(const double A[16], double out[16]) {
    double M[4][8];
    for (int r = 0; r < 4; ++r) {
        for (int c = 0; c < 4; ++c) M[r][c] = A[r*4+c];
        for (int c = 0; c < 4; ++c) M[r][4+c] = (r == c) ? 1.0 : 0.0;
    }
    for (int col = 0; col < 4; ++col) {
        int piv = col;
        double best = fabs(M[col][col]);
        for (int r = col+1; r < 4; ++r) {
            double v = fabs(M[r][col]);
            if (v > best) { best = v; piv = r; }
        }
        if (piv != col)
            for (int c = 0; c < 8; ++c) { double t = M[col][c]; M[col][c] = M[piv][c]; M[piv][c] = t; }
        double ip = 1.0 / M[col][col];
        for (int c = 0; c < 8; ++c) M[col][c] *= ip;
        for (int r = 0; r < 4; ++r) {
            if (r == col) continue;
            double f = M[r][col];
            if (f != 0.0)
                for (int c = 0; c < 8; ++c) M[r][c] -= f * M[col][c];
        }
    }
    for (int r = 0; r < 4; ++r)
        for (int c = 0; c < 4; ++c) out[r*4+c] = M[r][4+c];
}

__device__ inline void compute_rt(const float* proj, float* dst) {
    double Pref[16], Pinv[16];
    fold_mat(proj, Pref);
    inv4(Pref, Pinv);
    for (int v = 1; v < NVIEW; ++v) {
        double Ps[16], Pr[16];
        fold_mat(proj + v*32, Ps);
        for (int i = 0; i < 4; ++i)
            for (int j = 0; j < 4; ++j) {
                double s = 0.0;
                for (int k = 0; k < 4; ++k) s += Ps[i*4+k] * Pinv[k*4+j];
                Pr[i*4+j] = s;
            }
        float* o = dst + (v-1)*12;
        for (int i = 0; i < 3; ++i)
            for (int j = 0; j < 3; ++j) o[i*3+j] = (float)Pr[i*4+j];
        for (int i = 0; i < 3; ++i) o[9+i] = (float)Pr[i*4+3];
    }
}

// ---------- kernel 0: rt once ----------
__global__ void rt_kernel(const float* __restrict__ proj, float* __restrict__ rtbuf) {
    if (threadIdx.x == 0) compute_rt(proj, rtbuf);
}

// ---------- kernel 1: fused coords + transpose ----------
__global__ __launch_bounds__(256) void prep_kernel(
    const float* __restrict__ fea,     // (NVIEW, C, HW) fp32
    const float* __restrict__ depth,   // (D, HW)
    const float* __restrict__ rtbuf,   // 36 floats
    _Float16* __restrict__ feaH,       // (NVIEW, HW, C) fp16
    uint2* __restrict__ planeA,        // (3, TOTAL): {packed idx, packed w00w10}
    uint*  __restrict__ planeB)        // (3, TOTAL): packed w01w11
{
    const int b = blockIdx.x;
    if (b < COORD_BLOCKS) {
        // XCD-banded coords: xcd owns pixels [xcd*BAND, (xcd+1)*BAND)
        const int xcd  = b % NXCD;
        const int rest = b / NXCD;          // 0..1133
        const int v    = rest / 378;        // 0..2
        const int j    = rest % 378;
        const int local = j * 256 + threadIdx.x;   // 0..96767 = BAND*D
        const int ploc  = local % BAND;
        const int d     = local / BAND;
        const int p     = xcd * BAND + ploc;
        const int pd    = d * HW + p;

        const float* rt = rtbuf + v*12;
        const float fx = (float)(p % W);
        const float fy = (float)(p / W);
        const float dep = depth[pd];

        const float X = fmaf(fmaf(rt[0], fx, fmaf(rt[1], fy, rt[2])), dep, rt[9]);
        const float Y = fmaf(fmaf(rt[3], fx, fmaf(rt[4], fy, rt[5])), dep, rt[10]);
        const float Z = fmaf(fmaf(rt[6], fx, fmaf(rt[7], fy, rt[8])), dep, rt[11]);
        const float iZ = __builtin_amdgcn_rcpf(Z);
        const float px = X * iZ;
        const float py = Y * iZ;

        const float x0f = floorf(px), y0f = floorf(py);
        const float dx = px - x0f, dy = py - y0f;
        const int x0 = (int)x0f, y0 = (int)y0f;
        const int x1 = x0 + 1,  y1 = y0 + 1;

        float w00 = (1.f-dx)*(1.f-dy);
        float w10 = dx*(1.f-dy);
        float w01 = (1.f-dx)*dy;
        float w11 = dx*dy;

        const bool vx0 = (x0 >= 0) & (x0 < W);
        const bool vx1 = (x1 >= 0) & (x1 < W);
        const bool vy0 = (y0 >= 0) & (y0 < H);
        const bool vy1 = (y1 >= 0) & (y1 < H);
        if (!(vx0 && vy0)) w00 = 0.f;
        if (!(vx1 && vy0)) w10 = 0.f;
        if (!(vx0 && vy1)) w01 = 0.f;
        if (!(vx1 && vy1)) w11 = 0.f;

        // pre-clamped tap indices (weights already zero where invalid)
        const uint xc0 = (uint)min(max(x0, 0), W-1);
        const uint xc1 = (uint)min(max(x1, 0), W-1);
        const uint yc0 = (uint)min(max(y0, 0), H-1);
        const uint yc1 = (uint)min(max(y1, 0), H-1);
        const uint packed = xc0 | (xc1 << 8) | (yc0 << 16) | (yc1 << 24);

        h2 wa; wa.x = (_Float16)w00; wa.y = (_Float16)w10;
        h2 wb; wb.x = (_Float16)w01; wb.y = (_Float16)w11;

        const size_t idx = (size_t)v * TOTAL + pd;
        planeA[idx] = make_uint2(packed, h2u(wa));
        planeB[idx] = h2u(wb);
    } else {
        // transpose CHW fp32 -> HWC fp16
        const int t = (b - COORD_BLOCKS) * 256 + threadIdx.x;  // v*HW + p
        const int v = t / HW;
        const int p = t - v * HW;
        const float* src = fea + (size_t)v*C*HW + p;
        h8v ov[4];
        #pragma unroll
        for (int q = 0; q < 4; ++q) {
            #pragma unroll
            for (int k = 0; k < 8; ++k) ov[q][k] = (_Float16)src[(q*8+k)*HW];
        }
        h8v* dst = (h8v*)(feaH + (size_t)t * C);
        #pragma unroll
        for (int q = 0; q < 4; ++q) dst[q] = ov[q];
    }
}

// ---------- kernel 2: main gather+blend ----------
__global__ __launch_bounds__(256, 5) void gwc_main(
    const _Float16* __restrict__ feaH,   // (NVIEW, HW, C) fp16
    const uint2* __restrict__ planeA,
    const uint*  __restrict__ planeB,
    float* __restrict__ out)             // (G=8, D, HW)
{
    const int b    = blockIdx.x;
    const int xcd  = b % NXCD;
    const int j    = b / NXCD;
    const int wloc = j * WPB + (threadIdx.x >> 2);
    const int l    = threadIdx.x & 3;              // channel octet: groups 2l, 2l+1
    const int ploc = wloc % BAND;
    const int dc   = wloc / BAND;
    const int p    = xcd * BAND + ploc;
    const int pd0  = dc * DCHUNK * HW + p;

    // ref features: 16B (8 channels) for this lane
    h2 refq[4];
    {
        const h2* rp = (const h2*)(feaH + (size_t)p*C + l*8);
        refq[0] = rp[0]; refq[1] = rp[1]; refq[2] = rp[2]; refq[3] = rp[3];
    }

    // preload all 12 coord records (4 depths x 3 views)
    uint2 ca[DCHUNK][3];
    uint  cb[DCHUNK][3];
    #pragma unroll
    for (int dd = 0; dd < DCHUNK; ++dd) {
        const int pdi = pd0 + dd*HW;
        #pragma unroll
        for (int v = 0; v < 3; ++v) {
            const size_t idx = (size_t)v * TOTAL + pdi;
            ca[dd][v] = planeA[idx];
            cb[dd][v] = planeB[idx];
        }
    }

    const float scale = 1.f / 12.f;

    #pragma unroll
    for (int dd = 0; dd < DCHUNK; ++dd) {
        float accA = 0.f, accB = 0.f;
        #pragma unroll
        for (int v = 0; v < 3; ++v) {
            const uint xw = ca[dd][v].x;
            const h2 wa = u2h(ca[dd][v].y);
            const h2 wb = u2h(cb[dd][v]);

            const int xc0 = (int)(xw & 255u);
            const int xc1 = (int)((xw >> 8) & 255u);
            const int r0  = (int)((xw >> 16) & 255u) * W;
            const int r1  = (int)(xw >> 24) * W;

            const _Float16* bv = feaH + (size_t)(v+1)*HW*C + l*8;
            const h2x4 t00 = *(const h2x4*)(bv + (size_t)(r0+xc0)*C);
            const h2x4 t10 = *(const h2x4*)(bv + (size_t)(r0+xc1)*C);
            const h2x4 t01 = *(const h2x4*)(bv + (size_t)(r1+xc0)*C);
            const h2x4 t11 = *(const h2x4*)(bv + (size_t)(r1+xc1)*C);

            h2 w00s; w00s.x = wa.x; w00s.y = wa.x;
            h2 w10s; w10s.x = wa.y; w10s.y = wa.y;
            h2 w01s; w01s.x = wb.x; w01s.y = wb.x;
            h2 w11s; w11s.x = wb.y; w11s.y = wb.y;

            h2 s0 = w00s*t00.x + w10s*t10.x + w01s*t01.x + w11s*t11.x;
            h2 s1 = w00s*t00.y + w10s*t10.y + w01s*t01.y + w11s*t11.y;
            h2 s2 = w00s*t00.z + w10s*t10.z + w01s*t01.z + w11s*t11.z;
            h2 s3 = w00s*t00.w + w10s*t10.w + w01s*t01.w + w11s*t11.w;

            accA = dot2f(s0, refq[0], accA);
            accA = dot2f(s1, refq[1], accA);
            accB = dot2f(s2, refq[2], accB);
            accB = dot2f(s3, refq[3], accB);
        }
        const int pdi = pd0 + dd*HW;
        __builtin_nontemporal_store(accA * scale, &out[(2*l  )*TOTAL + pdi]);
        __builtin_nontemporal_store(accB * scale, &out[(2*l+1)*TOTAL + pdi]);
    }
}

// ---------- last-resort fallback (monolithic fp32) ----------
__global__ __launch_bounds__(256) void gwc_fallback(
    const float* __restrict__ fea,
    const float* __restrict__ proj,
    const float* __restrict__ depth,
    float* __restrict__ out)
{
    __shared__ float s_rt[(NVIEW-1)*12];
    if (threadIdx.x == 0) compute_rt(proj, s_rt);
    __syncthreads();

    const int tid = blockIdx.x * blockDim.x + threadIdx.x;
    const int p   = tid % HW;
    const float dep = depth[tid];
    const float fx = (float)(p % W);
    const float fy = (float)(p / W);

    float refv[C];
    #pragma unroll
    for (int c = 0; c < C; ++c) refv[c] = fea[c*HW + p];

    float acc[8];
    #pragma unroll
    for (int g = 0; g < 8; ++g) acc[g] = 0.f;

    #pragma unroll
    for (int v = 1; v < NVIEW; ++v) {
        const float* rt = s_rt + (v-1)*12;
        const float X = fmaf(fmaf(rt[0], fx, fmaf(rt[1], fy, rt[2])), dep, rt[9]);
        const float Y = fmaf(fmaf(rt[3], fx, fmaf(rt[4], fy, rt[5])), dep, rt[10]);
        const float Z = fmaf(fmaf(rt[6], fx, fmaf(rt[7], fy, rt[8])), dep, rt[11]);
        const float px = X / Z, py = Y / Z;
        const float x0f = floorf(px), y0f = floorf(py);
        const float dx = px - x0f, dy = py - y0f;
        const int x0 = (int)x0f, y0 = (int)y0f;
        const int x1 = x0 + 1,  y1 = y0 + 1;
        float w00 = (1.f-dx)*(1.f-dy), w10 = dx*(1.f-dy), w01 = (1.f-dx)*dy, w11 = dx*dy;
        const bool vx0 = (x0 >= 0) & (x0 < W), vx1 = (x1 >= 0) & (x1 < W);
        const bool vy0 = (y0 >= 0) & (y0 < H), vy1 = (y1 >= 0) & (y1 < H);
        if (!(vx0 && vy0)) w00 = 0.f;
        if (!(vx1 && vy0)) w10 = 0.f;
        if (!(vx0 && vy1)) w01 = 0.f;
        if (!(vx1 && vy1)) w11 = 0.f;
        const int xc0 = min(max(x0, 0), W-1), xc1 = min(max(x1, 0), W-1);
        const int yc0 = min(max(y0, 0), H-1), yc1 = min(max(y1, 0), H-1);
        const int o00 = yc0*W + xc0, o10 = yc0*W + xc1;
        const int o01 = yc1*W + xc0, o11 = yc1*W + xc1;
        const float* Fv = fea + v*(C*HW);
        #pragma unroll
        for (int c = 0; c < C; ++c) {
            const float* Fc = Fv + c*HW;
            const float s = w00*Fc[o00] + w10*Fc[o10] + w01*Fc[o01] + w11*Fc[o11];
            acc[c >> 2] = fmaf(s, refv[c], acc[c >> 2]);
        }
    }
    const float scale = 1.f / 12.f;
    #pragma unroll
    for (int g = 0; g < 8; ++g)
        out[g*TOTAL + tid] = acc[g] * scale;
}

extern "C" void kernel_launch(void* const* d_in, const int* in_sizes, int n_in,
                              void* d_out, int out_size, void* d_ws, size_t ws_size,
                              hipStream_t stream) {
    const float* fea   = (const float*)d_in[0];
    const float* proj  = (const float*)d_in[1];
    const float* depth = (const float*)d_in[2];
    float* out = (float*)d_out;
    char* ws = (char*)d_ws;

    if (ws_size >= WS_NEED) {
        _Float16* feaH = (_Float16*)ws;
        float*    rtb  = (float*)(ws + RT_OFF);
        uint2*    pA   = (uint2*)(ws + CA_OFF);
        uint*     pB   = (uint*)(ws + CB_OFF);
        rt_kernel<<<1, 64, 0, stream>>>(proj, rtb);
        prep_kernel<<<PREP_BLOCKS, 256, 0, stream>>>(fea, depth, rtb, feaH, pA, pB);
        gwc_main<<<MAIN_BLOCKS, 256, 0, stream>>>(feaH, pA, pB, out);
    } else {
        gwc_fallback<<<TOTAL/256, 256, 0, stream>>>(fea, proj, depth, out);
    }
}

// Round 10
// 45.924 us; speedup vs baseline: 1.4375x; 1.0335x over previous
//
#include <hip/hip_runtime.h>

// GroupWiseAgg: MVS group-wise correlation cost volume.
// features: (NVIEW=4, C=32, H=112, W=144) fp32
// proj:     (NVIEW, 2, 4, 4) fp32  [0]=extrinsic E, [1]=intrinsic K
// depth:    (D=48, H=112, W=144) fp32
// out:      (G=8, D, H, W) fp32
//
// R10 = R9 structure with:
//   - prep coords: ONE thread computes all 3 views per (d,p) (shared depth
//     load / fx / fy / index math): 3024 coord blocks instead of 9072.
//   - gwc_main: 64-thread (1-wave) blocks, launch_bounds(64,6) -> tests the
//     "2 blocks/CU residency cap" hypothesis behind the stuck 25% occupancy.

typedef _Float16 h2  __attribute__((ext_vector_type(2)));
typedef _Float16 h8v __attribute__((ext_vector_type(8)));
struct __attribute__((aligned(16))) h2x4 { h2 x, y, z, w; };

constexpr int NVIEW = 4;
constexpr int C     = 32;
constexpr int D     = 48;
constexpr int H     = 112;
constexpr int W     = 144;
constexpr int HW    = H * W;        // 16128
constexpr int TOTAL = D * HW;       // 774144
constexpr int DCHUNK = 4;
constexpr int NDC    = D / DCHUNK;  // 12
constexpr int NXCD   = 8;
constexpr int BAND   = HW / NXCD;   // 2016

// main: 64-thread blocks
constexpr int WPB64  = 16;                                  // wids per 64-thr block
constexpr int MAIN_BLOCKS = NXCD * ((BAND * NDC) / WPB64);  // 12096

// prep grid
constexpr int COORD_BLOCKS = TOTAL / 256;      // 3024 (one thread = 3 views)
constexpr int TRANS_BLOCKS = NVIEW * HW / 256; // 252
constexpr int PREP_BLOCKS  = COORD_BLOCKS + TRANS_BLOCKS;

// ws layout
constexpr size_t FEAH_BYTES = (size_t)NVIEW * HW * C * 2;   // 4,128,768
constexpr size_t RT_OFF     = FEAH_BYTES;
constexpr size_t CA_OFF     = RT_OFF + 256;
constexpr size_t CA_BYTES   = (size_t)3 * TOTAL * 8;        // packed idx + wA
constexpr size_t CB_OFF     = CA_OFF + CA_BYTES;
constexpr size_t CB_BYTES   = (size_t)3 * TOTAL * 4;        // wB
constexpr size_t WS_NEED    = CB_OFF + CB_BYTES;

#if __has_builtin(__builtin_amdgcn_fdot2)
__device__ inline float dot2f(h2 a, h2 b, float c) {
    return __builtin_amdgcn_fdot2(a, b, c, false);
}
#else
__device__ inline float dot2f(h2 a, h2 b, float c) {
    return fmaf((float)a.x, (float)b.x, fmaf((float)a.y, (float)b.y, c));
}
#endif

__device__ inline h2 u2h(uint v)  { union { uint u; h2 h; } x; x.u = v; return x.h; }
__device__ inline uint h2u(h2 v)  { union { uint u; h2 h; } x; x.h = v; return x.u; }

// ---------- matrix helpers ----------
__device__ inline void fold_mat(const float* pm, double out[16]) {
    const float* E = pm;
    const float* K = pm + 16;
    for (int i = 0; i < 3; ++i)
        for (int j = 0; j < 4; ++j) {
            double s = 0.0;
            for (int k = 0; k < 3; ++k) s += (double)K[i*4+k] * (double)E[k*4+j];
            out[i*4+j] = s;
        }
    for (int j = 0; j < 4; ++j) out[12+j] = (double)E[12+j];
}

__device__ inline void inv4(const double A[16], double out[16]) {
    double M[4][8];
    for (int r = 0; r < 4; ++r) {
        for (int c = 0; c < 4; ++c) M[r][c] = A[r*4+c];
        for (int c = 0; c < 4; ++c) M[r][4+c] = (r == c) ? 1.0 : 0.0;
    }
    for (int col = 0; col < 4; ++col) {
        int piv = col;
        double best = fabs(M[col][col]);
        for (int r = col+1; r < 4; ++r) {
            double v = fabs(M[r][col]);
            if (v > best) { best = v; piv = r; }
        }
        if (piv != col)
            for (int c = 0; c < 8; ++c) { double t = M[col][c]; M[col][c] = M[piv][c]; M[piv][c] = t; }
        double ip = 1.0 / M[col][col];
        for (int c = 0; c < 8; ++c) M[col][c] *= ip;
        for (int r = 0; r < 4; ++r) {
            if (r == col) continue;
            double f = M[r][col];
            if (f != 0.0)
                for (int c = 0; c < 8; ++c) M[r][c] -= f * M[col][c];
        }
    }
    for (int r = 0; r < 4; ++r)
        for (int c = 0; c < 4; ++c) out[r*4+c] = M[r][4+c];
}

__device__ inline void compute_rt(const float* proj, float* dst) {
    double Pref[16], Pinv[16];
    fold_mat(proj, Pref);
    inv4(Pref, Pinv);
    for (int v = 1; v < NVIEW; ++v) {
        double Ps[16], Pr[16];
        fold_mat(proj + v*32, Ps);
        for (int i = 0; i < 4; ++i)
            for (int j = 0; j < 4; ++j) {
                double s = 0.0;
                for (int k = 0; k < 4; ++k) s += Ps[i*4+k] * Pinv[k*4+j];
                Pr[i*4+j] = s;
            }
        float* o = dst + (v-1)*12;
        for (int i = 0; i < 3; ++i)
            for (int j = 0; j < 3; ++j) o[i*3+j] = (float)Pr[i*4+j];
        for (int i = 0; i < 3; ++i) o[9+i] = (float)Pr[i*4+3];
    }
}

// ---------- kernel 0: rt once ----------
__global__ void rt_kernel(const float* __restrict__ proj, float* __restrict__ rtbuf) {
    if (threadIdx.x == 0) compute_rt(proj, rtbuf);
}

// ---------- kernel 1: fused coords (3 views/thread) + transpose ----------
__global__ __launch_bounds__(256) void prep_kernel(
    const float* __restrict__ fea,     // (NVIEW, C, HW) fp32
    const float* __restrict__ depth,   // (D, HW)
    const float* __restrict__ rtbuf,   // 36 floats
    _Float16* __restrict__ feaH,       // (NVIEW, HW, C) fp16
    uint2* __restrict__ planeA,        // (3, TOTAL): {packed idx, packed w00w10}
    uint*  __restrict__ planeB)        // (3, TOTAL): packed w01w11
{
    const int b = blockIdx.x;
    if (b < COORD_BLOCKS) {
        // XCD-banded: xcd owns pixels [xcd*BAND, (xcd+1)*BAND)
        const int xcd  = b % NXCD;
        const int j    = b / NXCD;                 // 0..377
        const int local = j * 256 + threadIdx.x;   // 0..96767 = BAND*D
        const int ploc  = local % BAND;
        const int d     = local / BAND;
        const int p     = xcd * BAND + ploc;
        const int pd    = d * HW + p;

        const float fx = (float)(p % W);
        const float fy = (float)(p / W);
        const float dep = depth[pd];

        #pragma unroll
        for (int v = 0; v < 3; ++v) {
            const float* rt = rtbuf + v*12;
            const float X = fmaf(fmaf(rt[0], fx, fmaf(rt[1], fy, rt[2])), dep, rt[9]);
            const float Y = fmaf(fmaf(rt[3], fx, fmaf(rt[4], fy, rt[5])), dep, rt[10]);
            const float Z = fmaf(fmaf(rt[6], fx, fmaf(rt[7], fy, rt[8])), dep, rt[11]);
            const float iZ = __builtin_amdgcn_rcpf(Z);
            const float px = X * iZ;
            const float py = Y * iZ;

            const float x0f = floorf(px), y0f = floorf(py);
            const float dx = px - x0f, dy = py - y0f;
            const int x0 = (int)x0f, y0 = (int)y0f;
            const int x1 = x0 + 1,  y1 = y0 + 1;

            float w00 = (1.f-dx)*(1.f-dy);
            float w10 = dx*(1.f-dy);
            float w01 = (1.f-dx)*dy;
            float w11 = dx*dy;

            const bool vx0 = (x0 >= 0) & (x0 < W);
            const bool vx1 = (x1 >= 0) & (x1 < W);
            const bool vy0 = (y0 >= 0) & (y0 < H);
            const bool vy1 = (y1 >= 0) & (y1 < H);
            if (!(vx0 && vy0)) w00 = 0.f;
            if (!(vx1 && vy0)) w10 = 0.f;
            if (!(vx0 && vy1)) w01 = 0.f;
            if (!(vx1 && vy1)) w11 = 0.f;

            const uint xc0 = (uint)min(max(x0, 0), W-1);
            const uint xc1 = (uint)min(max(x1, 0), W-1);
            const uint yc0 = (uint)min(max(y0, 0), H-1);
            const uint yc1 = (uint)min(max(y1, 0), H-1);
            const uint packed = xc0 | (xc1 << 8) | (yc0 << 16) | (yc1 << 24);

            h2 wa; wa.x = (_Float16)w00; wa.y = (_Float16)w10;
            h2 wb; wb.x = (_Float16)w01; wb.y = (_Float16)w11;

            const size_t idx = (size_t)v * TOTAL + pd;
            planeA[idx] = make_uint2(packed, h2u(wa));
            planeB[idx] = h2u(wb);
        }
    } else {
        // transpose CHW fp32 -> HWC fp16
        const int t = (b - COORD_BLOCKS) * 256 + threadIdx.x;  // v*HW + p
        const int v = t / HW;
        const int p = t - v * HW;
        const float* src = fea + (size_t)v*C*HW + p;
        h8v ov[4];
        #pragma unroll
        for (int q = 0; q < 4; ++q) {
            #pragma unroll
            for (int k = 0; k < 8; ++k) ov[q][k] = (_Float16)src[(q*8+k)*HW];
        }
        h8v* dst = (h8v*)(feaH + (size_t)t * C);
        #pragma unroll
        for (int q = 0; q < 4; ++q) dst[q] = ov[q];
    }
}

// ---------- kernel 2: main gather+blend (1-wave blocks) ----------
__global__ __launch_bounds__(64, 6) void gwc_main(
    const _Float16* __restrict__ feaH,   // (NVIEW, HW, C) fp16
    const uint2* __restrict__ planeA,
    const uint*  __restrict__ planeB,
    float* __restrict__ out)             // (G=8, D, HW)
{
    const int b    = blockIdx.x;
    const int xcd  = b % NXCD;
    const int j    = b / NXCD;                      // 0..1511
    const int wloc = j * WPB64 + (threadIdx.x >> 2);
    const int l    = threadIdx.x & 3;               // channel octet: groups 2l, 2l+1
    const int ploc = wloc % BAND;
    const int dc   = wloc / BAND;
    const int p    = xcd * BAND + ploc;
    const int pd0  = dc * DCHUNK * HW + p;

    // ref features: 16B (8 channels) for this lane
    h2 refq[4];
    {
        const h2* rp = (const h2*)(feaH + (size_t)p*C + l*8);
        refq[0] = rp[0]; refq[1] = rp[1]; refq[2] = rp[2]; refq[3] = rp[3];
    }

    // preload all 12 coord records (4 depths x 3 views)
    uint2 ca[DCHUNK][3];
    uint  cb[DCHUNK][3];
    #pragma unroll
    for (int dd = 0; dd < DCHUNK; ++dd) {
        const int pdi = pd0 + dd*HW;
        #pragma unroll
        for (int v = 0; v < 3; ++v) {
            const size_t idx = (size_t)v * TOTAL + pdi;
            ca[dd][v] = planeA[idx];
            cb[dd][v] = planeB[idx];
        }
    }

    const float scale = 1.f / 12.f;

    #pragma unroll
    for (int dd = 0; dd < DCHUNK; ++dd) {
        float accA = 0.f, accB = 0.f;
        #pragma unroll
        for (int v = 0; v < 3; ++v) {
            const uint xw = ca[dd][v].x;
            const h2 wa = u2h(ca[dd][v].y);
            const h2 wb = u2h(cb[dd][v]);

            const int xc0 = (int)(xw & 255u);
            const int xc1 = (int)((xw >> 8) & 255u);
            const int r0  = (int)((xw >> 16) & 255u) * W;
            const int r1  = (int)(xw >> 24) * W;

            const _Float16* bv = feaH + (size_t)(v+1)*HW*C + l*8;
            const h2x4 t00 = *(const h2x4*)(bv + (size_t)(r0+xc0)*C);
            const h2x4 t10 = *(const h2x4*)(bv + (size_t)(r0+xc1)*C);
            const h2x4 t01 = *(const h2x4*)(bv + (size_t)(r1+xc0)*C);
            const h2x4 t11 = *(const h2x4*)(bv + (size_t)(r1+xc1)*C);

            h2 w00s; w00s.x = wa.x; w00s.y = wa.x;
            h2 w10s; w10s.x = wa.y; w10s.y = wa.y;
            h2 w01s; w01s.x = wb.x; w01s.y = wb.x;
            h2 w11s; w11s.x = wb.y; w11s.y = wb.y;

            h2 s0 = w00s*t00.x + w10s*t10.x + w01s*t01.x + w11s*t11.x;
            h2 s1 = w00s*t00.y + w10s*t10.y + w01s*t01.y + w11s*t11.y;
            h2 s2 = w00s*t00.z + w10s*t10.z + w01s*t01.z + w11s*t11.z;
            h2 s3 = w00s*t00.w + w10s*t10.w + w01s*t01.w + w11s*t11.w;

            accA = dot2f(s0, refq[0], accA);
            accA = dot2f(s1, refq[1], accA);
            accB = dot2f(s2, refq[2], accB);
            accB = dot2f(s3, refq[3], accB);
        }
        const int pdi = pd0 + dd*HW;
        __builtin_nontemporal_store(accA * scale, &out[(2*l  )*TOTAL + pdi]);
        __builtin_nontemporal_store(accB * scale, &out[(2*l+1)*TOTAL + pdi]);
    }
}

// ---------- last-resort fallback (monolithic fp32) ----------
__global__ __launch_bounds__(256) void gwc_fallback(
    const float* __restrict__ fea,
    const float* __restrict__ proj,
    const float* __restrict__ depth,
    float* __restrict__ out)
{
    __shared__ float s_rt[(NVIEW-1)*12];
    if (threadIdx.x == 0) compute_rt(proj, s_rt);
    __syncthreads();

    const int tid = blockIdx.x * blockDim.x + threadIdx.x;
    const int p   = tid % HW;
    const float dep = depth[tid];
    const float fx = (float)(p % W);
    const float fy = (float)(p / W);

    float refv[C];
    #pragma unroll
    for (int c = 0; c < C; ++c) refv[c] = fea[c*HW + p];

    float acc[8];
    #pragma unroll
    for (int g = 0; g < 8; ++g) acc[g] = 0.f;

    #pragma unroll
    for (int v = 1; v < NVIEW; ++v) {
        const float* rt = s_rt + (v-1)*12;
        const float X = fmaf(fmaf(rt[0], fx, fmaf(rt[1], fy, rt[2])), dep, rt[9]);
        const float Y = fmaf(fmaf(rt[3], fx, fmaf(rt[4], fy, rt[5])), dep, rt[10]);
        const float Z = fmaf(fmaf(rt[6], fx, fmaf(rt[7], fy, rt[8])), dep, rt[11]);
        const float px = X / Z, py = Y / Z;
        const float x0f = floorf(px), y0f = floorf(py);
        const float dx = px - x0f, dy = py - y0f;
        const int x0 = (int)x0f, y0 = (int)y0f;
        const int x1 = x0 + 1,  y1 = y0 + 1;
        float w00 = (1.f-dx)*(1.f-dy), w10 = dx*(1.f-dy), w01 = (1.f-dx)*dy, w11 = dx*dy;
        const bool vx0 = (x0 >= 0) & (x0 < W), vx1 = (x1 >= 0) & (x1 < W);
        const bool vy0 = (y0 >= 0) & (y0 < H), vy1 = (y1 >= 0) & (y1 < H);
        if (!(vx0 && vy0)) w00 = 0.f;
        if (!(vx1 && vy0)) w10 = 0.f;
        if (!(vx0 && vy1)) w01 = 0.f;
        if (!(vx1 && vy1)) w11 = 0.f;
        const int xc0 = min(max(x0, 0), W-1), xc1 = min(max(x1, 0), W-1);
        const int yc0 = min(max(y0, 0), H-1), yc1 = min(max(y1, 0), H-1);
        const int o00 = yc0*W + xc0, o10 = yc0*W + xc1;
        const int o01 = yc1*W + xc0, o11 = yc1*W + xc1;
        const float* Fv = fea + v*(C*HW);
        #pragma unroll
        for (int c = 0; c < C; ++c) {
            const float* Fc = Fv + c*HW;
            const float s = w00*Fc[o00] + w10*Fc[o10] + w01*Fc[o01] + w11*Fc[o11];
            acc[c >> 2] = fmaf(s, refv[c], acc[c >> 2]);
        }
    }
    const float scale = 1.f / 12.f;
    #pragma unroll
    for (int g = 0; g < 8; ++g)
        out[g*TOTAL + tid] = acc[g] * scale;
}

extern "C" void kernel_launch(void* const* d_in, const int* in_sizes, int n_in,
                              void* d_out, int out_size, void* d_ws, size_t ws_size,
                              hipStream_t stream) {
    const float* fea   = (const float*)d_in[0];
    const float* proj  = (const float*)d_in[1];
    const float* depth = (const float*)d_in[2];
    float* out = (float*)d_out;
    char* ws = (char*)d_ws;

    if (ws_size >= WS_NEED) {
        _Float16* feaH = (_Float16*)ws;
        float*    rtb  = (float*)(ws + RT_OFF);
        uint2*    pA   = (uint2*)(ws + CA_OFF);
        uint*     pB   = (uint*)(ws + CB_OFF);
        rt_kernel<<<1, 64, 0, stream>>>(proj, rtb);
        prep_kernel<<<PREP_BLOCKS, 256, 0, stream>>>(fea, depth, rtb, feaH, pA, pB);
        gwc_main<<<MAIN_BLOCKS, 64, 0, stream>>>(feaH, pA, pB, out);
    } else {
        gwc_fallback<<<TOTAL/256, 256, 0, stream>>>(fea, proj, depth, out);
    }
}

// Round 11
// 43.381 us; speedup vs baseline: 1.5217x; 1.0586x over previous
//
#include <hip/hip_runtime.h>

// GroupWiseAgg: MVS group-wise correlation cost volume.
// features: (NVIEW=4, C=32, H=112, W=144) fp32
// proj:     (NVIEW, 2, 4, 4) fp32  [0]=extrinsic E, [1]=intrinsic K
// depth:    (D=48, H=112, W=144) fp32
// out:      (G=8, D, H, W) fp32
//
// R11 = R10 with rt_kernel ELIMINATED: folded projections have row3 =
// [0,0,0,1] (P = [[M t],[0 1]]), so src@inv(ref) has the closed form
// rot = Ms*Mr^-1 (3x3 adjugate), trans = ts - rot*tr. Each coord block
// computes it inline on thread 0 (~150 fp64 ops, ILP-rich) -> 2 launches
// total, no rt kernel, one fewer graph gap. Main kernel unchanged from R10.

typedef _Float16 h2  __attribute__((ext_vector_type(2)));
typedef _Float16 h8v __attribute__((ext_vector_type(8)));
struct __attribute__((aligned(16))) h2x4 { h2 x, y, z, w; };

constexpr int NVIEW = 4;
constexpr int C     = 32;
constexpr int D     = 48;
constexpr int H     = 112;
constexpr int W     = 144;
constexpr int HW    = H * W;        // 16128
constexpr int TOTAL = D * HW;       // 774144
constexpr int DCHUNK = 4;
constexpr int NDC    = D / DCHUNK;  // 12
constexpr int NXCD   = 8;
constexpr int BAND   = HW / NXCD;   // 2016

// main: 64-thread blocks
constexpr int WPB64  = 16;                                  // wids per 64-thr block
constexpr int MAIN_BLOCKS = NXCD * ((BAND * NDC) / WPB64);  // 12096

// prep grid
constexpr int COORD_BLOCKS = TOTAL / 256;      // 3024 (one thread = 3 views)
constexpr int TRANS_BLOCKS = NVIEW * HW / 256; // 252
constexpr int PREP_BLOCKS  = COORD_BLOCKS + TRANS_BLOCKS;

// ws layout
constexpr size_t FEAH_BYTES = (size_t)NVIEW * HW * C * 2;   // 4,128,768
constexpr size_t CA_OFF     = ((FEAH_BYTES + 255) / 256) * 256;
constexpr size_t CA_BYTES   = (size_t)3 * TOTAL * 8;        // packed idx + wA
constexpr size_t CB_OFF     = CA_OFF + CA_BYTES;
constexpr size_t CB_BYTES   = (size_t)3 * TOTAL * 4;        // wB
constexpr size_t WS_NEED    = CB_OFF + CB_BYTES;

#if __has_builtin(__builtin_amdgcn_fdot2)
__device__ inline float dot2f(h2 a, h2 b, float c) {
    return __builtin_amdgcn_fdot2(a, b, c, false);
}
#else
__device__ inline float dot2f(h2 a, h2 b, float c) {
    return fmaf((float)a.x, (float)b.x, fmaf((float)a.y, (float)b.y, c));
}
#endif

__device__ inline h2 u2h(uint v)  { union { uint u; h2 h; } x; x.u = v; return x.h; }
__device__ inline uint h2u(h2 v)  { union { uint u; h2 h; } x; x.h = v; return x.u; }

// ---------- fast rt: exploits P = [[M t],[0 1]] structure ----------
// fold: M = K3x3 * E[:3,:3], t = K3x3 * E[:3,3]
__device__ inline void fold_Mt(const float* pm, double M[9], double t[3]) {
    const float* E = pm;        // extrinsic
    const float* K = pm + 16;   // intrinsic
    for (int i = 0; i < 3; ++i) {
        for (int j = 0; j < 3; ++j) {
            double s = 0.0;
            for (int k = 0; k < 3; ++k) s += (double)K[i*4+k] * (double)E[k*4+j];
            M[i*3+j] = s;
        }
        double s = 0.0;
        for (int k = 0; k < 3; ++k) s += (double)K[i*4+k] * (double)E[k*4+3];
        t[i] = s;
    }
}

// 3x3 inverse via adjugate (det != 0: det = det(K3)*det(R) = 250000)
__device__ inline void inv3(const double M[9], double out[9]) {
    const double c00 =  (M[4]*M[8] - M[5]*M[7]);
    const double c01 = -(M[3]*M[8] - M[5]*M[6]);
    const double c02 =  (M[3]*M[7] - M[4]*M[6]);
    const double det = M[0]*c00 + M[1]*c01 + M[2]*c02;
    const double id = 1.0 / det;
    out[0] = c00 * id;
    out[3] = c01 * id;
    out[6] = c02 * id;
    out[1] = -(M[1]*M[8] - M[2]*M[7]) * id;
    out[4] =  (M[0]*M[8] - M[2]*M[6]) * id;
    out[7] = -(M[0]*M[7] - M[1]*M[6]) * id;
    out[2] =  (M[1]*M[5] - M[2]*M[4]) * id;
    out[5] = -(M[0]*M[5] - M[2]*M[3]) * id;
    out[8] =  (M[0]*M[4] - M[1]*M[3]) * id;
}

// rt for v=1..3: rot = Ms*Mrinv, trans = ts - rot*tr  -> dst[36]
__device__ inline void compute_rt_fast(const float* proj, float* dst) {
    double Mr[9], tr[3], Mrinv[9];
    fold_Mt(proj, Mr, tr);
    inv3(Mr, Mrinv);
    for (int v = 1; v < NVIEW; ++v) {
        double Ms[9], ts[3];
        fold_Mt(proj + v*32, Ms, ts);
        float* o = dst + (v-1)*12;
        double rot[9];
        for (int i = 0; i < 3; ++i)
            for (int j = 0; j < 3; ++j) {
                double s = 0.0;
                for (int k = 0; k < 3; ++k) s += Ms[i*3+k] * Mrinv[k*3+j];
                rot[i*3+j] = s;
                o[i*3+j] = (float)s;
            }
        for (int i = 0; i < 3; ++i) {
            double s = ts[i];
            for (int k = 0; k < 3; ++k) s -= rot[i*3+k] * tr[k];
            o[9+i] = (float)s;
        }
    }
}

// ---------- kernel 1: fused coords (3 views/thread, inline rt) + transpose ----------
__global__ __launch_bounds__(256) void prep_kernel(
    const float* __restrict__ fea,     // (NVIEW, C, HW) fp32
    const float* __restrict__ depth,   // (D, HW)
    const float* __restrict__ proj,    // (NVIEW, 2, 4, 4)
    _Float16* __restrict__ feaH,       // (NVIEW, HW, C) fp16
    uint2* __restrict__ planeA,        // (3, TOTAL): {packed idx, packed w00w10}
    uint*  __restrict__ planeB)        // (3, TOTAL): packed w01w11
{
    const int b = blockIdx.x;
    if (b < COORD_BLOCKS) {
        __shared__ float s_rt[36];
        if (threadIdx.x == 0) compute_rt_fast(proj, s_rt);
        __syncthreads();

        // XCD-banded: xcd owns pixels [xcd*BAND, (xcd+1)*BAND)
        const int xcd  = b % NXCD;
        const int j    = b / NXCD;                 // 0..377
        const int local = j * 256 + threadIdx.x;   // 0..96767 = BAND*D
        const int ploc  = local % BAND;
        const int d     = local / BAND;
        const int p     = xcd * BAND + ploc;
        const int pd    = d * HW + p;

        const float fx = (float)(p % W);
        const float fy = (float)(p / W);
        const float dep = depth[pd];

        #pragma unroll
        for (int v = 0; v < 3; ++v) {
            const float* rt = s_rt + v*12;
            const float X = fmaf(fmaf(rt[0], fx, fmaf(rt[1], fy, rt[2])), dep, rt[9]);
            const float Y = fmaf(fmaf(rt[3], fx, fmaf(rt[4], fy, rt[5])), dep, rt[10]);
            const float Z = fmaf(fmaf(rt[6], fx, fmaf(rt[7], fy, rt[8])), dep, rt[11]);
            const float iZ = __builtin_amdgcn_rcpf(Z);
            const float px = X * iZ;
            const float py = Y * iZ;

            const float x0f = floorf(px), y0f = floorf(py);
            const float dx = px - x0f, dy = py - y0f;
            const int x0 = (int)x0f, y0 = (int)y0f;
            const int x1 = x0 + 1,  y1 = y0 + 1;

            float w00 = (1.f-dx)*(1.f-dy);
            float w10 = dx*(1.f-dy);
            float w01 = (1.f-dx)*dy;
            float w11 = dx*dy;

            const bool vx0 = (x0 >= 0) & (x0 < W);
            const bool vx1 = (x1 >= 0) & (x1 < W);
            const bool vy0 = (y0 >= 0) & (y0 < H);
            const bool vy1 = (y1 >= 0) & (y1 < H);
            if (!(vx0 && vy0)) w00 = 0.f;
            if (!(vx1 && vy0)) w10 = 0.f;
            if (!(vx0 && vy1)) w01 = 0.f;
            if (!(vx1 && vy1)) w11 = 0.f;

            const uint xc0 = (uint)min(max(x0, 0), W-1);
            const uint xc1 = (uint)min(max(x1, 0), W-1);
            const uint yc0 = (uint)min(max(y0, 0), H-1);
            const uint yc1 = (uint)min(max(y1, 0), H-1);
            const uint packed = xc0 | (xc1 << 8) | (yc0 << 16) | (yc1 << 24);

            h2 wa; wa.x = (_Float16)w00; wa.y = (_Float16)w10;
            h2 wb; wb.x = (_Float16)w01; wb.y = (_Float16)w11;

            const size_t idx = (size_t)v * TOTAL + pd;
            planeA[idx] = make_uint2(packed, h2u(wa));
            planeB[idx] = h2u(wb);
        }
    } else {
        // transpose CHW fp32 -> HWC fp16
        const int t = (b - COORD_BLOCKS) * 256 + threadIdx.x;  // v*HW + p
        const int v = t / HW;
        const int p = t - v * HW;
        const float* src = fea + (size_t)v*C*HW + p;
        h8v ov[4];
        #pragma unroll
        for (int q = 0; q < 4; ++q) {
            #pragma unroll
            for (int k = 0; k < 8; ++k) ov[q][k] = (_Float16)src[(q*8+k)*HW];
        }
        h8v* dst = (h8v*)(feaH + (size_t)t * C);
        #pragma unroll
        for (int q = 0; q < 4; ++q) dst[q] = ov[q];
    }
}

// ---------- kernel 2: main gather+blend (1-wave blocks, unchanged R10) ----------
__global__ __launch_bounds__(64, 6) void gwc_main(
    const _Float16* __restrict__ feaH,   // (NVIEW, HW, C) fp16
    const uint2* __restrict__ planeA,
    const uint*  __restrict__ planeB,
    float* __restrict__ out)             // (G=8, D, HW)
{
    const int b    = blockIdx.x;
    const int xcd  = b % NXCD;
    const int j    = b / NXCD;                      // 0..1511
    const int wloc = j * WPB64 + (threadIdx.x >> 2);
    const int l    = threadIdx.x & 3;               // channel octet: groups 2l, 2l+1
    const int ploc = wloc % BAND;
    const int dc   = wloc / BAND;
    const int p    = xcd * BAND + ploc;
    const int pd0  = dc * DCHUNK * HW + p;

    // ref features: 16B (8 channels) for this lane
    h2 refq[4];
    {
        const h2* rp = (const h2*)(feaH + (size_t)p*C + l*8);
        refq[0] = rp[0]; refq[1] = rp[1]; refq[2] = rp[2]; refq[3] = rp[3];
    }

    // preload all 12 coord records (4 depths x 3 views)
    uint2 ca[DCHUNK][3];
    uint  cb[DCHUNK][3];
    #pragma unroll
    for (int dd = 0; dd < DCHUNK; ++dd) {
        const int pdi = pd0 + dd*HW;
        #pragma unroll
        for (int v = 0; v < 3; ++v) {
            const size_t idx = (size_t)v * TOTAL + pdi;
            ca[dd][v] = planeA[idx];
            cb[dd][v] = planeB[idx];
        }
    }

    const float scale = 1.f / 12.f;

    #pragma unroll
    for (int dd = 0; dd < DCHUNK; ++dd) {
        float accA = 0.f, accB = 0.f;
        #pragma unroll
        for (int v = 0; v < 3; ++v) {
            const uint xw = ca[dd][v].x;
            const h2 wa = u2h(ca[dd][v].y);
            const h2 wb = u2h(cb[dd][v]);

            const int xc0 = (int)(xw & 255u);
            const int xc1 = (int)((xw >> 8) & 255u);
            const int r0  = (int)((xw >> 16) & 255u) * W;
            const int r1  = (int)(xw >> 24) * W;

            const _Float16* bv = feaH + (size_t)(v+1)*HW*C + l*8;
            const h2x4 t00 = *(const h2x4*)(bv + (size_t)(r0+xc0)*C);
            const h2x4 t10 = *(const h2x4*)(bv + (size_t)(r0+xc1)*C);
            const h2x4 t01 = *(const h2x4*)(bv + (size_t)(r1+xc0)*C);
            const h2x4 t11 = *(const h2x4*)(bv + (size_t)(r1+xc1)*C);

            h2 w00s; w00s.x = wa.x; w00s.y = wa.x;
            h2 w10s; w10s.x = wa.y; w10s.y = wa.y;
            h2 w01s; w01s.x = wb.x; w01s.y = wb.x;
            h2 w11s; w11s.x = wb.y; w11s.y = wb.y;

            h2 s0 = w00s*t00.x + w10s*t10.x + w01s*t01.x + w11s*t11.x;
            h2 s1 = w00s*t00.y + w10s*t10.y + w01s*t01.y + w11s*t11.y;
            h2 s2 = w00s*t00.z + w10s*t10.z + w01s*t01.z + w11s*t11.z;
            h2 s3 = w00s*t00.w + w10s*t10.w + w01s*t01.w + w11s*t11.w;

            accA = dot2f(s0, refq[0], accA);
            accA = dot2f(s1, refq[1], accA);
            accB = dot2f(s2, refq[2], accB);
            accB = dot2f(s3, refq[3], accB);
        }
        const int pdi = pd0 + dd*HW;
        __builtin_nontemporal_store(accA * scale, &out[(2*l  )*TOTAL + pdi]);
        __builtin_nontemporal_store(accB * scale, &out[(2*l+1)*TOTAL + pdi]);
    }
}

// ---------- last-resort fallback (monolithic fp32, self-contained) ----------
__global__ __launch_bounds__(256) void gwc_fallback(
    const float* __restrict__ fea,
    const float* __restrict__ proj,
    const float* __restrict__ depth,
    float* __restrict__ out)
{
    __shared__ float s_rt[36];
    if (threadIdx.x == 0) compute_rt_fast(proj, s_rt);
    __syncthreads();

    const int tid = blockIdx.x * blockDim.x + threadIdx.x;
    const int p   = tid % HW;
    const float dep = depth[tid];
    const float fx = (float)(p % W);
    const float fy = (float)(p / W);

    float refv[C];
    #pragma unroll
    for (int c = 0; c < C; ++c) refv[c] = fea[c*HW + p];

    float acc[8];
    #pragma unroll
    for (int g = 0; g < 8; ++g) acc[g] = 0.f;

    #pragma unroll
    for (int v = 1; v < NVIEW; ++v) {
        const float* rt = s_rt + (v-1)*12;
        const float X = fmaf(fmaf(rt[0], fx, fmaf(rt[1], fy, rt[2])), dep, rt[9]);
        const float Y = fmaf(fmaf(rt[3], fx, fmaf(rt[4], fy, rt[5])), dep, rt[10]);
        const float Z = fmaf(fmaf(rt[6], fx, fmaf(rt[7], fy, rt[8])), dep, rt[11]);
        const float px = X / Z, py = Y / Z;
        const float x0f = floorf(px), y0f = floorf(py);
        const float dx = px - x0f, dy = py - y0f;
        const int x0 = (int)x0f, y0 = (int)y0f;
        const int x1 = x0 + 1,  y1 = y0 + 1;
        float w00 = (1.f-dx)*(1.f-dy), w10 = dx*(1.f-dy), w01 = (1.f-dx)*dy, w11 = dx*dy;
        const bool vx0 = (x0 >= 0) & (x0 < W), vx1 = (x1 >= 0) & (x1 < W);
        const bool vy0 = (y0 >= 0) & (y0 < H), vy1 = (y1 >= 0) & (y1 < H);
        if (!(vx0 && vy0)) w00 = 0.f;
        if (!(vx1 && vy0)) w10 = 0.f;
        if (!(vx0 && vy1)) w01 = 0.f;
        if (!(vx1 && vy1)) w11 = 0.f;
        const int xc0 = min(max(x0, 0), W-1), xc1 = min(max(x1, 0), W-1);
        const int yc0 = min(max(y0, 0), H-1), yc1 = min(max(y1, 0), H-1);
        const int o00 = yc0*W + xc0, o10 = yc0*W + xc1;
        const int o01 = yc1*W + xc0, o11 = yc1*W + xc1;
        const float* Fv = fea + v*(C*HW);
        #pragma unroll
        for (int c = 0; c < C; ++c) {
            const float* Fc = Fv + c*HW;
            const float s = w00*Fc[o00] + w10*Fc[o10] + w01*Fc[o01] + w11*Fc[o11];
            acc[c >> 2] = fmaf(s, refv[c], acc[c >> 2]);
        }
    }
    const float scale = 1.f / 12.f;
    #pragma unroll
    for (int g = 0; g < 8; ++g)
        out[g*TOTAL + tid] = acc[g] * scale;
}

extern "C" void kernel_launch(void* const* d_in, const int* in_sizes, int n_in,
                              void* d_out, int out_size, void* d_ws, size_t ws_size,
                              hipStream_t stream) {
    const float* fea   = (const float*)d_in[0];
    const float* proj  = (const float*)d_in[1];
    const float* depth = (const float*)d_in[2];
    float* out = (float*)d_out;
    char* ws = (char*)d_ws;

    if (ws_size >= WS_NEED) {
        _Float16* feaH = (_Float16*)ws;
        uint2*    pA   = (uint2*)(ws + CA_OFF);
        uint*     pB   = (uint*)(ws + CB_OFF);
        prep_kernel<<<PREP_BLOCKS, 256, 0, stream>>>(fea, depth, proj, feaH, pA, pB);
        gwc_main<<<MAIN_BLOCKS, 64, 0, stream>>>(feaH, pA, pB, out);
    } else {
        gwc_fallback<<<TOTAL/256, 256, 0, stream>>>(fea, proj, depth, out);
    }
}

// Round 13
// 41.723 us; speedup vs baseline: 1.5822x; 1.0397x over previous
//
#include <hip/hip_runtime.h>

// GroupWiseAgg: MVS group-wise correlation cost volume.
// features: (NVIEW=4, C=32, H=112, W=144) fp32
// proj:     (NVIEW, 2, 4, 4) fp32  [0]=extrinsic E, [1]=intrinsic K
// depth:    (D=48, H=112, W=144) fp32
// out:      (G=8, D, H, W) fp32
//
// R13 = R12 with the encoding bug fixed: x_base range is -1..143 which does
// NOT fit signed i8 (143 -> -113). Store (xb+1) in 0..144 and (yb+1) in
// 0..112 as UNSIGNED bytes; decode with -1. Everything else identical:
//   record = {u8 xb+1, u8 yb+1, valid nibble, fp16 dx, fp16 dy} (8B)
//   taps: xc0=max(xb,0), xc1=min(xb+1,W-1); weights recomputed fp32 in main.

typedef _Float16 h2  __attribute__((ext_vector_type(2)));
typedef _Float16 h8v __attribute__((ext_vector_type(8)));
struct __attribute__((aligned(16))) h2x4 { h2 x, y, z, w; };

constexpr int NVIEW = 4;
constexpr int C     = 32;
constexpr int D     = 48;
constexpr int H     = 112;
constexpr int W     = 144;
constexpr int HW    = H * W;        // 16128
constexpr int TOTAL = D * HW;       // 774144
constexpr int DCHUNK = 4;
constexpr int NDC    = D / DCHUNK;  // 12
constexpr int NXCD   = 8;
constexpr int BAND   = HW / NXCD;   // 2016

// main: 64-thread blocks
constexpr int WPB64  = 16;                                  // wids per 64-thr block
constexpr int MAIN_BLOCKS = NXCD * ((BAND * NDC) / WPB64);  // 12096

// prep grid
constexpr int COORD_BLOCKS = TOTAL / 256;      // 3024 (one thread = 3 views)
constexpr int TRANS_BLOCKS = NVIEW * HW / 256; // 252
constexpr int PREP_BLOCKS  = COORD_BLOCKS + TRANS_BLOCKS;

// ws layout
constexpr size_t FEAH_BYTES = (size_t)NVIEW * HW * C * 2;   // 4,128,768
constexpr size_t CR_OFF     = ((FEAH_BYTES + 255) / 256) * 256;
constexpr size_t CR_BYTES   = (size_t)3 * TOTAL * 8;        // 18.6 MB
constexpr size_t WS_NEED    = CR_OFF + CR_BYTES;

#if __has_builtin(__builtin_amdgcn_fdot2)
__device__ inline float dot2f(h2 a, h2 b, float c) {
    return __builtin_amdgcn_fdot2(a, b, c, false);
}
#else
__device__ inline float dot2f(h2 a, h2 b, float c) {
    return fmaf((float)a.x, (float)b.x, fmaf((float)a.y, (float)b.y, c));
}
#endif

__device__ inline h2 u2h(uint v)  { union { uint u; h2 h; } x; x.u = v; return x.h; }
__device__ inline uint h2u(h2 v)  { union { uint u; h2 h; } x; x.h = v; return x.u; }

// ---------- fast rt: exploits P = [[M t],[0 1]] structure ----------
__device__ inline void fold_Mt(const float* pm, double M[9], double t[3]) {
    const float* E = pm;        // extrinsic
    const float* K = pm + 16;   // intrinsic
    for (int i = 0; i < 3; ++i) {
        for (int j = 0; j < 3; ++j) {
            double s = 0.0;
            for (int k = 0; k < 3; ++k) s += (double)K[i*4+k] * (double)E[k*4+j];
            M[i*3+j] = s;
        }
        double s = 0.0;
        for (int k = 0; k < 3; ++k) s += (double)K[i*4+k] * (double)E[k*4+3];
        t[i] = s;
    }
}

__device__ inline void inv3(const double M[9], double out[9]) {
    const double c00 =  (M[4]*M[8] - M[5]*M[7]);
    const double c01 = -(M[3]*M[8] - M[5]*M[6]);
    const double c02 =  (M[3]*M[7] - M[4]*M[6]);
    const double det = M[0]*c00 + M[1]*c01 + M[2]*c02;
    const double id = 1.0 / det;
    out[0] = c00 * id;
    out[3] = c01 * id;
    out[6] = c02 * id;
    out[1] = -(M[1]*M[8] - M[2]*M[7]) * id;
    out[4] =  (M[0]*M[8] - M[2]*M[6]) * id;
    out[7] = -(M[0]*M[7] - M[1]*M[6]) * id;
    out[2] =  (M[1]*M[5] - M[2]*M[4]) * id;
    out[5] = -(M[0]*M[5] - M[2]*M[3]) * id;
    out[8] =  (M[0]*M[4] - M[1]*M[3]) * id;
}

__device__ inline void compute_rt_fast(const float* proj, float* dst) {
    double Mr[9], tr[3], Mrinv[9];
    fold_Mt(proj, Mr, tr);
    inv3(Mr, Mrinv);
    for (int v = 1; v < NVIEW; ++v) {
        double Ms[9], ts[3];
        fold_Mt(proj + v*32, Ms, ts);
        float* o = dst + (v-1)*12;
        double rot[9];
        for (int i = 0; i < 3; ++i)
            for (int j = 0; j < 3; ++j) {
                double s = 0.0;
                for (int k = 0; k < 3; ++k) s += Ms[i*3+k] * Mrinv[k*3+j];
                rot[i*3+j] = s;
                o[i*3+j] = (float)s;
            }
        for (int i = 0; i < 3; ++i) {
            double s = ts[i];
            for (int k = 0; k < 3; ++k) s -= rot[i*3+k] * tr[k];
            o[9+i] = (float)s;
        }
    }
}

// ---------- kernel 1: fused coords (3 views/thread, 8B records) + transpose ----------
__global__ __launch_bounds__(256) void prep_kernel(
    const float* __restrict__ fea,     // (NVIEW, C, HW) fp32
    const float* __restrict__ depth,   // (D, HW)
    const float* __restrict__ proj,    // (NVIEW, 2, 4, 4)
    _Float16* __restrict__ feaH,       // (NVIEW, HW, C) fp16
    uint2* __restrict__ planeR)        // (3, TOTAL): 8B records
{
    const int b = blockIdx.x;
    if (b < COORD_BLOCKS) {
        __shared__ float s_rt[36];
        if (threadIdx.x == 0) compute_rt_fast(proj, s_rt);
        __syncthreads();

        // XCD-banded: xcd owns pixels [xcd*BAND, (xcd+1)*BAND)
        const int xcd  = b % NXCD;
        const int j    = b / NXCD;                 // 0..377
        const int local = j * 256 + threadIdx.x;   // 0..96767 = BAND*D
        const int ploc  = local % BAND;
        const int d     = local / BAND;
        const int p     = xcd * BAND + ploc;
        const int pd    = d * HW + p;

        const float fx = (float)(p % W);
        const float fy = (float)(p / W);
        const float dep = depth[pd];

        #pragma unroll
        for (int v = 0; v < 3; ++v) {
            const float* rt = s_rt + v*12;
            const float X = fmaf(fmaf(rt[0], fx, fmaf(rt[1], fy, rt[2])), dep, rt[9]);
            const float Y = fmaf(fmaf(rt[3], fx, fmaf(rt[4], fy, rt[5])), dep, rt[10]);
            const float Z = fmaf(fmaf(rt[6], fx, fmaf(rt[7], fy, rt[8])), dep, rt[11]);
            const float iZ = __builtin_amdgcn_rcpf(Z);
            const float px = X * iZ;
            const float py = Y * iZ;

            const float x0f = floorf(px), y0f = floorf(py);
            const float dx = px - x0f, dy = py - y0f;
            const int x0 = (int)x0f, y0 = (int)y0f;
            const int x1 = x0 + 1,  y1 = y0 + 1;

            const bool vx0 = (x0 >= 0) & (x0 < W);
            const bool vx1 = (x1 >= 0) & (x1 < W);
            const bool vy0 = (y0 >= 0) & (y0 < H);
            const bool vy1 = (y1 >= 0) & (y1 < H);
            const uint vb = (uint)(vx0 && vy0)
                          | ((uint)(vx1 && vy0) << 1)
                          | ((uint)(vx0 && vy1) << 2)
                          | ((uint)(vx1 && vy1) << 3);

            // base indices biased by +1 -> UNSIGNED ranges 0..144 / 0..112
            // (signed i8 overflows at 143: R12's bug)
            const int xb1 = min(max(x0, -1), W-1) + 1;   // 0..144
            const int yb1 = min(max(y0, -1), H-1) + 1;   // 0..112

            const uint lo = (uint)xb1 | ((uint)yb1 << 8) | (vb << 16);
            h2 dxy; dxy.x = (_Float16)dx; dxy.y = (_Float16)dy;

            planeR[(size_t)v * TOTAL + pd] = make_uint2(lo, h2u(dxy));
        }
    } else {
        // transpose CHW fp32 -> HWC fp16
        const int t = (b - COORD_BLOCKS) * 256 + threadIdx.x;  // v*HW + p
        const int v = t / HW;
        const int p = t - v * HW;
        const float* src = fea + (size_t)v*C*HW + p;
        h8v ov[4];
        #pragma unroll
        for (int q = 0; q < 4; ++q) {
            #pragma unroll
            for (int k = 0; k < 8; ++k) ov[q][k] = (_Float16)src[(q*8+k)*HW];
        }
        h8v* dst = (h8v*)(feaH + (size_t)t * C);
        #pragma unroll
        for (int q = 0; q < 4; ++q) dst[q] = ov[q];
    }
}

// ---------- kernel 2: main gather+blend (1-wave blocks) ----------
__global__ __launch_bounds__(64, 6) void gwc_main(
    const _Float16* __restrict__ feaH,   // (NVIEW, HW, C) fp16
    const uint2* __restrict__ planeR,    // (3, TOTAL) 8B records
    float* __restrict__ out)             // (G=8, D, HW)
{
    const int b    = blockIdx.x;
    const int xcd  = b % NXCD;
    const int j    = b / NXCD;                      // 0..1511
    const int wloc = j * WPB64 + (threadIdx.x >> 2);
    const int l    = threadIdx.x & 3;               // channel octet: groups 2l, 2l+1
    const int ploc = wloc % BAND;
    const int dc   = wloc / BAND;
    const int p    = xcd * BAND + ploc;
    const int pd0  = dc * DCHUNK * HW + p;

    // ref features: 16B (8 channels) for this lane
    h2 refq[4];
    {
        const h2* rp = (const h2*)(feaH + (size_t)p*C + l*8);
        refq[0] = rp[0]; refq[1] = rp[1]; refq[2] = rp[2]; refq[3] = rp[3];
    }

    // preload all 12 coord records (4 depths x 3 views), 8B each
    uint2 cr[DCHUNK][3];
    #pragma unroll
    for (int dd = 0; dd < DCHUNK; ++dd) {
        const int pdi = pd0 + dd*HW;
        #pragma unroll
        for (int v = 0; v < 3; ++v)
            cr[dd][v] = planeR[(size_t)v * TOTAL + pdi];
    }

    const float scale = 1.f / 12.f;

    #pragma unroll
    for (int dd = 0; dd < DCHUNK; ++dd) {
        float accA = 0.f, accB = 0.f;
        #pragma unroll
        for (int v = 0; v < 3; ++v) {
            const uint lo = cr[dd][v].x;
            const h2 dxy = u2h(cr[dd][v].y);

            const int xb = (int)(lo & 0xFFu) - 1;          // -1..143
            const int yb = (int)((lo >> 8) & 0xFFu) - 1;   // -1..111
            const uint vb = (lo >> 16) & 0xFu;

            const int xc0 = max(xb, 0),     xc1 = min(xb + 1, W-1);
            const int yc0 = max(yb, 0),     yc1 = min(yb + 1, H-1);
            const int r0  = yc0 * W,        r1  = yc1 * W;

            // recompute weights in fp32 from fp16 dx,dy; mask by valid bits
            const float dx = (float)dxy.x, dy = (float)dxy.y;
            const float omx = 1.f - dx,    omy = 1.f - dy;
            float w00 = omx*omy, w10 = dx*omy, w01 = omx*dy, w11 = dx*dy;
            w00 = (vb & 1u) ? w00 : 0.f;
            w10 = (vb & 2u) ? w10 : 0.f;
            w01 = (vb & 4u) ? w01 : 0.f;
            w11 = (vb & 8u) ? w11 : 0.f;

            const _Float16* bv = feaH + (size_t)(v+1)*HW*C + l*8;
            const h2x4 t00 = *(const h2x4*)(bv + (size_t)(r0+xc0)*C);
            const h2x4 t10 = *(const h2x4*)(bv + (size_t)(r0+xc1)*C);
            const h2x4 t01 = *(const h2x4*)(bv + (size_t)(r1+xc0)*C);
            const h2x4 t11 = *(const h2x4*)(bv + (size_t)(r1+xc1)*C);

            h2 w00s; w00s.x = (_Float16)w00; w00s.y = w00s.x;
            h2 w10s; w10s.x = (_Float16)w10; w10s.y = w10s.x;
            h2 w01s; w01s.x = (_Float16)w01; w01s.y = w01s.x;
            h2 w11s; w11s.x = (_Float16)w11; w11s.y = w11s.x;

            h2 s0 = w00s*t00.x + w10s*t10.x + w01s*t01.x + w11s*t11.x;
            h2 s1 = w00s*t00.y + w10s*t10.y + w01s*t01.y + w11s*t11.y;
            h2 s2 = w00s*t00.z + w10s*t10.z + w01s*t01.z + w11s*t11.z;
            h2 s3 = w00s*t00.w + w10s*t10.w + w01s*t01.w + w11s*t11.w;

            accA = dot2f(s0, refq[0], accA);
            accA = dot2f(s1, refq[1], accA);
            accB = dot2f(s2, refq[2], accB);
            accB = dot2f(s3, refq[3], accB);
        }
        const int pdi = pd0 + dd*HW;
        __builtin_nontemporal_store(accA * scale, &out[(2*l  )*TOTAL + pdi]);
        __builtin_nontemporal_store(accB * scale, &out[(2*l+1)*TOTAL + pdi]);
    }
}

// ---------- last-resort fallback (monolithic fp32, self-contained) ----------
__global__ __launch_bounds__(256) void gwc_fallback(
    const float* __restrict__ fea,
    const float* __restrict__ proj,
    const float* __restrict__ depth,
    float* __restrict__ out)
{
    __shared__ float s_rt[36];
    if (threadIdx.x == 0) compute_rt_fast(proj, s_rt);
    __syncthreads();

    const int tid = blockIdx.x * blockDim.x + threadIdx.x;
    const int p   = tid % HW;
    const float dep = depth[tid];
    const float fx = (float)(p % W);
    const float fy = (float)(p / W);

    float refv[C];
    #pragma unroll
    for (int c = 0; c < C; ++c) refv[c] = fea[c*HW + p];

    float acc[8];
    #pragma unroll
    for (int g = 0; g < 8; ++g) acc[g] = 0.f;

    #pragma unroll
    for (int v = 1; v < NVIEW; ++v) {
        const float* rt = s_rt + (v-1)*12;
        const float X = fmaf(fmaf(rt[0], fx, fmaf(rt[1], fy, rt[2])), dep, rt[9]);
        const float Y = fmaf(fmaf(rt[3], fx, fmaf(rt[4], fy, rt[5])), dep, rt[10]);
        const float Z = fmaf(fmaf(rt[6], fx, fmaf(rt[7], fy, rt[8])), dep, rt[11]);
        const float px = X / Z, py = Y / Z;
        const float x0f = floorf(px), y0f = floorf(py);
        const float dx = px - x0f, dy = py - y0f;
        const int x0 = (int)x0f, y0 = (int)y0f;
        const int x1 = x0 + 1,  y1 = y0 + 1;
        float w00 = (1.f-dx)*(1.f-dy), w10 = dx*(1.f-dy), w01 = (1.f-dx)*dy, w11 = dx*dy;
        const bool vx0 = (x0 >= 0) & (x0 < W), vx1 = (x1 >= 0) & (x1 < W);
        const bool vy0 = (y0 >= 0) & (y0 < H), vy1 = (y1 >= 0) & (y1 < H);
        if (!(vx0 && vy0)) w00 = 0.f;
        if (!(vx1 && vy0)) w10 = 0.f;
        if (!(vx0 && vy1)) w01 = 0.f;
        if (!(vx1 && vy1)) w11 = 0.f;
        const int xc0 = min(max(x0, 0), W-1), xc1 = min(max(x1, 0), W-1);
        const int yc0 = min(max(y0, 0), H-1), yc1 = min(max(y1, 0), H-1);
        const int o00 = yc0*W + xc0, o10 = yc0*W + xc1;
        const int o01 = yc1*W + xc0, o11 = yc1*W + xc1;
        const float* Fv = fea + v*(C*HW);
        #pragma unroll
        for (int c = 0; c < C; ++c) {
            const float* Fc = Fv + c*HW;
            const float s = w00*Fc[o00] + w10*Fc[o10] + w01*Fc[o01] + w11*Fc[o11];
            acc[c >> 2] = fmaf(s, refv[c], acc[c >> 2]);
        }
    }
    const float scale = 1.f / 12.f;
    #pragma unroll
    for (int g = 0; g < 8; ++g)
        out[g*TOTAL + tid] = acc[g] * scale;
}

extern "C" void kernel_launch(void* const* d_in, const int* in_sizes, int n_in,
                              void* d_out, int out_size, void* d_ws, size_t ws_size,
                              hipStream_t stream) {
    const float* fea   = (const float*)d_in[0];
    const float* proj  = (const float*)d_in[1];
    const float* depth = (const float*)d_in[2];
    float* out = (float*)d_out;
    char* ws = (char*)d_ws;

    if (ws_size >= WS_NEED) {
        _Float16* feaH = (_Float16*)ws;
        uint2*    pR   = (uint2*)(ws + CR_OFF);
        prep_kernel<<<PREP_BLOCKS, 256, 0, stream>>>(fea, depth, proj, feaH, pR);
        gwc_main<<<MAIN_BLOCKS, 64, 0, stream>>>(feaH, pR, out);
    } else {
        gwc_fallback<<<TOTAL/256, 256, 0, stream>>>(fea, proj, depth, out);
    }
}

// Round 15
// 32.967 us; speedup vs baseline: 2.0024x; 1.2656x over previous
//
#include <hip/hip_runtime.h>

// GroupWiseAgg: MVS group-wise correlation cost volume.
// features: (NVIEW=4, C=32, H=112, W=144) fp32
// proj:     (NVIEW, 2, 4, 4) fp32  [0]=extrinsic E, [1]=intrinsic K
// depth:    (D=48, H=112, W=144) fp32
// out:      (G=8, D, H, W) fp32
//
// R15 = R14 with the readfirstlane bug fixed: the builtin takes i32, so a
// float argument was VALUE-converted (truncated) not bitcast. Use a union
// bitcast. Everything else identical to R14:
//   - prep: transpose only (+1 rt block) -> ~1.5 us
//   - main: lane l computes coords for depth dd=l (3 views, non-redundant),
//     12 records distributed via __shfl (wave-internal, no barrier),
//     weights from fp32 dx/dy, taps from fp16 HWC buffer.

typedef _Float16 h2  __attribute__((ext_vector_type(2)));
typedef _Float16 h8v __attribute__((ext_vector_type(8)));
struct __attribute__((aligned(16))) h2x4 { h2 x, y, z, w; };

constexpr int NVIEW = 4;
constexpr int C     = 32;
constexpr int D     = 48;
constexpr int H     = 112;
constexpr int W     = 144;
constexpr int HW    = H * W;        // 16128
constexpr int TOTAL = D * HW;       // 774144
constexpr int DCHUNK = 4;
constexpr int NDC    = D / DCHUNK;  // 12
constexpr int NXCD   = 8;
constexpr int BAND   = HW / NXCD;   // 2016

// main: 64-thread blocks
constexpr int WPB64  = 16;                                  // wids per 64-thr block
constexpr int MAIN_BLOCKS = NXCD * ((BAND * NDC) / WPB64);  // 12096

// prep grid: transpose + 1 rt block
constexpr int TRANS_BLOCKS = NVIEW * HW / 256; // 252
constexpr int PREP_BLOCKS  = TRANS_BLOCKS + 1;

// ws layout
constexpr size_t FEAH_BYTES = (size_t)NVIEW * HW * C * 2;   // 4,128,768
constexpr size_t RT_OFF     = ((FEAH_BYTES + 255) / 256) * 256;
constexpr size_t WS_NEED    = RT_OFF + 256;

#if __has_builtin(__builtin_amdgcn_fdot2)
__device__ inline float dot2f(h2 a, h2 b, float c) {
    return __builtin_amdgcn_fdot2(a, b, c, false);
}
#else
__device__ inline float dot2f(h2 a, h2 b, float c) {
    return fmaf((float)a.x, (float)b.x, fmaf((float)a.y, (float)b.y, c));
}
#endif

// readfirstlane for float: BITCAST, not value-convert (R14's bug)
__device__ inline float rfl_f32(float v) {
    union { float f; int i; } u;
    u.f = v;
    u.i = __builtin_amdgcn_readfirstlane(u.i);
    return u.f;
}

// ---------- fast rt: exploits P = [[M t],[0 1]] structure ----------
__device__ inline void fold_Mt(const float* pm, double M[9], double t[3]) {
    const float* E = pm;        // extrinsic
    const float* K = pm + 16;   // intrinsic
    for (int i = 0; i < 3; ++i) {
        for (int j = 0; j < 3; ++j) {
            double s = 0.0;
            for (int k = 0; k < 3; ++k) s += (double)K[i*4+k] * (double)E[k*4+j];
            M[i*3+j] = s;
        }
        double s = 0.0;
        for (int k = 0; k < 3; ++k) s += (double)K[i*4+k] * (double)E[k*4+3];
        t[i] = s;
    }
}

__device__ inline void inv3(const double M[9], double out[9]) {
    const double c00 =  (M[4]*M[8] - M[5]*M[7]);
    const double c01 = -(M[3]*M[8] - M[5]*M[6]);
    const double c02 =  (M[3]*M[7] - M[4]*M[6]);
    const double det = M[0]*c00 + M[1]*c01 + M[2]*c02;
    const double id = 1.0 / det;
    out[0] = c00 * id;
    out[3] = c01 * id;
    out[6] = c02 * id;
    out[1] = -(M[1]*M[8] - M[2]*M[7]) * id;
    out[4] =  (M[0]*M[8] - M[2]*M[6]) * id;
    out[7] = -(M[0]*M[7] - M[1]*M[6]) * id;
    out[2] =  (M[1]*M[5] - M[2]*M[4]) * id;
    out[5] = -(M[0]*M[5] - M[2]*M[3]) * id;
    out[8] =  (M[0]*M[4] - M[1]*M[3]) * id;
}

__device__ inline void compute_rt_fast(const float* proj, float* dst) {
    double Mr[9], tr[3], Mrinv[9];
    fold_Mt(proj, Mr, tr);
    inv3(Mr, Mrinv);
    for (int v = 1; v < NVIEW; ++v) {
        double Ms[9], ts[3];
        fold_Mt(proj + v*32, Ms, ts);
        float* o = dst + (v-1)*12;
        double rot[9];
        for (int i = 0; i < 3; ++i)
            for (int j = 0; j < 3; ++j) {
                double s = 0.0;
                for (int k = 0; k < 3; ++k) s += Ms[i*3+k] * Mrinv[k*3+j];
                rot[i*3+j] = s;
                o[i*3+j] = (float)s;
            }
        for (int i = 0; i < 3; ++i) {
            double s = ts[i];
            for (int k = 0; k < 3; ++k) s -= rot[i*3+k] * tr[k];
            o[9+i] = (float)s;
        }
    }
}

// ---------- kernel 1: transpose CHW fp32 -> HWC fp16 (+1 rt block) ----------
__global__ __launch_bounds__(256) void prep_kernel(
    const float* __restrict__ fea,     // (NVIEW, C, HW) fp32
    const float* __restrict__ proj,    // (NVIEW, 2, 4, 4)
    _Float16* __restrict__ feaH,       // (NVIEW, HW, C) fp16
    float* __restrict__ rtws)          // 36 floats
{
    const int b = blockIdx.x;
    if (b < TRANS_BLOCKS) {
        const int t = b * 256 + threadIdx.x;  // v*HW + p
        const int v = t / HW;
        const int p = t - v * HW;
        const float* src = fea + (size_t)v*C*HW + p;
        h8v ov[4];
        #pragma unroll
        for (int q = 0; q < 4; ++q) {
            #pragma unroll
            for (int k = 0; k < 8; ++k) ov[q][k] = (_Float16)src[(q*8+k)*HW];
        }
        h8v* dst = (h8v*)(feaH + (size_t)t * C);
        #pragma unroll
        for (int q = 0; q < 4; ++q) dst[q] = ov[q];
    } else {
        if (threadIdx.x == 0) compute_rt_fast(proj, rtws);
    }
}

// ---------- kernel 2: main (coords in-lane, shfl distribution) ----------
__global__ __launch_bounds__(64, 4) void gwc_main(
    const _Float16* __restrict__ feaH,   // (NVIEW, HW, C) fp16
    const float* __restrict__ rtg,       // 36 floats (ws)
    const float* __restrict__ depth,     // (D, HW)
    float* __restrict__ out)             // (G=8, D, HW)
{
    const int b    = blockIdx.x;
    const int xcd  = b % NXCD;
    const int j    = b / NXCD;                      // 0..1511
    const int tid  = threadIdx.x;
    const int wloc = j * WPB64 + (tid >> 2);
    const int l    = tid & 3;                       // channel octet AND depth-lane
    const int ploc = wloc % BAND;
    const int dc   = wloc / BAND;
    const int p    = xcd * BAND + ploc;
    const int pd0  = dc * DCHUNK * HW + p;

    // rt into SGPRs (uniform) -- BITCAST readfirstlane
    float srt[36];
    #pragma unroll
    for (int k = 0; k < 36; ++k)
        srt[k] = rfl_f32(rtg[k]);

    // ref features: 16B (8 channels) for this lane
    h2 refq[4];
    {
        const h2* rp = (const h2*)(feaH + (size_t)p*C + l*8);
        refq[0] = rp[0]; refq[1] = rp[1]; refq[2] = rp[2]; refq[3] = rp[3];
    }

    // ---- lane-parallel coords: this lane handles depth dd = l ----
    const float fx = (float)(p % W);
    const float fy = (float)(p / W);
    const float dep = depth[pd0 + l*HW];

    uint  rec_lo[3];
    float rec_dx[3], rec_dy[3];
    #pragma unroll
    for (int v = 0; v < 3; ++v) {
        const float* rt = srt + v*12;
        const float X = fmaf(fmaf(rt[0], fx, fmaf(rt[1], fy, rt[2])), dep, rt[9]);
        const float Y = fmaf(fmaf(rt[3], fx, fmaf(rt[4], fy, rt[5])), dep, rt[10]);
        const float Z = fmaf(fmaf(rt[6], fx, fmaf(rt[7], fy, rt[8])), dep, rt[11]);
        const float iZ = __builtin_amdgcn_rcpf(Z);
        const float px = X * iZ;
        const float py = Y * iZ;

        const float x0f = floorf(px), y0f = floorf(py);
        const float dx = px - x0f, dy = py - y0f;
        const int x0 = (int)x0f, y0 = (int)y0f;
        const int x1 = x0 + 1,  y1 = y0 + 1;

        const bool vx0 = (x0 >= 0) & (x0 < W);
        const bool vx1 = (x1 >= 0) & (x1 < W);
        const bool vy0 = (y0 >= 0) & (y0 < H);
        const bool vy1 = (y1 >= 0) & (y1 < H);
        const uint vb = (uint)(vx0 && vy0)
                      | ((uint)(vx1 && vy0) << 1)
                      | ((uint)(vx0 && vy1) << 2)
                      | ((uint)(vx1 && vy1) << 3);

        const int xb1 = min(max(x0, -1), W-1) + 1;   // 0..144 (unsigned byte)
        const int yb1 = min(max(y0, -1), H-1) + 1;   // 0..112

        rec_lo[v] = (uint)xb1 | ((uint)yb1 << 8) | (vb << 16);
        rec_dx[v] = dx;
        rec_dy[v] = dy;
    }

    const int base = tid & ~3;   // cluster base lane
    const float scale = 1.f / 12.f;

    #pragma unroll
    for (int dd = 0; dd < DCHUNK; ++dd) {
        float accA = 0.f, accB = 0.f;
        #pragma unroll
        for (int v = 0; v < 3; ++v) {
            const uint  lo = (uint)__shfl((int)rec_lo[v], base + dd);
            const float dx = __shfl(rec_dx[v], base + dd);
            const float dy = __shfl(rec_dy[v], base + dd);

            const int xb = (int)(lo & 0xFFu) - 1;          // -1..143
            const int yb = (int)((lo >> 8) & 0xFFu) - 1;   // -1..111
            const uint vb = (lo >> 16) & 0xFu;

            const int xc0 = max(xb, 0),     xc1 = min(xb + 1, W-1);
            const int yc0 = max(yb, 0),     yc1 = min(yb + 1, H-1);
            const int r0  = yc0 * W,        r1  = yc1 * W;

            const float omx = 1.f - dx,    omy = 1.f - dy;
            float w00 = omx*omy, w10 = dx*omy, w01 = omx*dy, w11 = dx*dy;
            w00 = (vb & 1u) ? w00 : 0.f;
            w10 = (vb & 2u) ? w10 : 0.f;
            w01 = (vb & 4u) ? w01 : 0.f;
            w11 = (vb & 8u) ? w11 : 0.f;

            const _Float16* bv = feaH + (size_t)(v+1)*HW*C + l*8;
            const h2x4 t00 = *(const h2x4*)(bv + (size_t)(r0+xc0)*C);
            const h2x4 t10 = *(const h2x4*)(bv + (size_t)(r0+xc1)*C);
            const h2x4 t01 = *(const h2x4*)(bv + (size_t)(r1+xc0)*C);
            const h2x4 t11 = *(const h2x4*)(bv + (size_t)(r1+xc1)*C);

            h2 w00s; w00s.x = (_Float16)w00; w00s.y = w00s.x;
            h2 w10s; w10s.x = (_Float16)w10; w10s.y = w10s.x;
            h2 w01s; w01s.x = (_Float16)w01; w01s.y = w01s.x;
            h2 w11s; w11s.x = (_Float16)w11; w11s.y = w11s.x;

            h2 s0 = w00s*t00.x + w10s*t10.x + w01s*t01.x + w11s*t11.x;
            h2 s1 = w00s*t00.y + w10s*t10.y + w01s*t01.y + w11s*t11.y;
            h2 s2 = w00s*t00.z + w10s*t10.z + w01s*t01.z + w11s*t11.z;
            h2 s3 = w00s*t00.w + w10s*t10.w + w01s*t01.w + w11s*t11.w;

            accA = dot2f(s0, refq[0], accA);
            accA = dot2f(s1, refq[1], accA);
            accB = dot2f(s2, refq[2], accB);
            accB = dot2f(s3, refq[3], accB);
        }
        const int pdi = pd0 + dd*HW;
        __builtin_nontemporal_store(accA * scale, &out[(2*l  )*TOTAL + pdi]);
        __builtin_nontemporal_store(accB * scale, &out[(2*l+1)*TOTAL + pdi]);
    }
}

// ---------- last-resort fallback (monolithic fp32, self-contained) ----------
__global__ __launch_bounds__(256) void gwc_fallback(
    const float* __restrict__ fea,
    const float* __restrict__ proj,
    const float* __restrict__ depth,
    float* __restrict__ out)
{
    __shared__ float s_rt[36];
    if (threadIdx.x == 0) compute_rt_fast(proj, s_rt);
    __syncthreads();

    const int tid = blockIdx.x * blockDim.x + threadIdx.x;
    const int p   = tid % HW;
    const float dep = depth[tid];
    const float fx = (float)(p % W);
    const float fy = (float)(p / W);

    float refv[C];
    #pragma unroll
    for (int c = 0; c < C; ++c) refv[c] = fea[c*HW + p];

    float acc[8];
    #pragma unroll
    for (int g = 0; g < 8; ++g) acc[g] = 0.f;

    #pragma unroll
    for (int v = 1; v < NVIEW; ++v) {
        const float* rt = s_rt + (v-1)*12;
        const float X = fmaf(fmaf(rt[0], fx, fmaf(rt[1], fy, rt[2])), dep, rt[9]);
        const float Y = fmaf(fmaf(rt[3], fx, fmaf(rt[4], fy, rt[5])), dep, rt[10]);
        const float Z = fmaf(fmaf(rt[6], fx, fmaf(rt[7], fy, rt[8])), dep, rt[11]);
        const float px = X / Z, py = Y / Z;
        const float x0f = floorf(px), y0f = floorf(py);
        const float dx = px - x0f, dy = py - y0f;
        const int x0 = (int)x0f, y0 = (int)y0f;
        const int x1 = x0 + 1,  y1 = y0 + 1;
        float w00 = (1.f-dx)*(1.f-dy), w10 = dx*(1.f-dy), w01 = (1.f-dx)*dy, w11 = dx*dy;
        const bool vx0 = (x0 >= 0) & (x0 < W), vx1 = (x1 >= 0) & (x1 < W);
        const bool vy0 = (y0 >= 0) & (y0 < H), vy1 = (y1 >= 0) & (y1 < H);
        if (!(vx0 && vy0)) w00 = 0.f;
        if (!(vx1 && vy0)) w10 = 0.f;
        if (!(vx0 && vy1)) w01 = 0.f;
        if (!(vx1 && vy1)) w11 = 0.f;
        const int xc0 = min(max(x0, 0), W-1), xc1 = min(max(x1, 0), W-1);
        const int yc0 = min(max(y0, 0), H-1), yc1 = min(max(y1, 0), H-1);
        const int o00 = yc0*W + xc0, o10 = yc0*W + xc1;
        const int o01 = yc1*W + xc0, o11 = yc1*W + xc1;
        const float* Fv = fea + v*(C*HW);
        #pragma unroll
        for (int c = 0; c < C; ++c) {
            const float* Fc = Fv + c*HW;
            const float s = w00*Fc[o00] + w10*Fc[o10] + w01*Fc[o01] + w11*Fc[o11];
            acc[c >> 2] = fmaf(s, refv[c], acc[c >> 2]);
        }
    }
    const float scale = 1.f / 12.f;
    #pragma unroll
    for (int g = 0; g < 8; ++g)
        out[g*TOTAL + tid] = acc[g] * scale;
}

extern "C" void kernel_launch(void* const* d_in, const int* in_sizes, int n_in,
                              void* d_out, int out_size, void* d_ws, size_t ws_size,
                              hipStream_t stream) {
    const float* fea   = (const float*)d_in[0];
    const float* proj  = (const float*)d_in[1];
    const float* depth = (const float*)d_in[2];
    float* out = (float*)d_out;
    char* ws = (char*)d_ws;

    if (ws_size >= WS_NEED) {
        _Float16* feaH = (_Float16*)ws;
        float*    rtw  = (float*)(ws + RT_OFF);
        prep_kernel<<<PREP_BLOCKS, 256, 0, stream>>>(fea, proj, feaH, rtw);
        gwc_main<<<MAIN_BLOCKS, 64, 0, stream>>>(feaH, rtw, depth, out);
    } else {
        gwc_fallback<<<TOTAL/256, 256, 0, stream>>>(fea, proj, depth, out);
    }
}

// Round 16
// 32.332 us; speedup vs baseline: 2.0417x; 1.0196x over previous
//
#include <hip/hip_runtime.h>

// GroupWiseAgg: MVS group-wise correlation cost volume.
// features: (NVIEW=4, C=32, H=112, W=144) fp32
// proj:     (NVIEW, 2, 4, 4) fp32  [0]=extrinsic E, [1]=intrinsic K
// depth:    (D=48, H=112, W=144) fp32
// out:      (G=8, D, H, W) fp32
//
// R16 = R15 with record unpacking de-duplicated: the owning lane (depth
// dd=l) now precomputes per view the 4 FINAL element offsets ((r+x)*C) and
// the 2 packed fp16 weight words (validity zeros baked). Distribution is 6
// shfl words per (dd,v); consumers only add l*8 to offsets. Removes ~300
// redundant VALU/thread (clamps, row-muls, weight products, h2 splats).

typedef _Float16 h2  __attribute__((ext_vector_type(2)));
typedef _Float16 h8v __attribute__((ext_vector_type(8)));
struct __attribute__((aligned(16))) h2x4 { h2 x, y, z, w; };

constexpr int NVIEW = 4;
constexpr int C     = 32;
constexpr int D     = 48;
constexpr int H     = 112;
constexpr int W     = 144;
constexpr int HW    = H * W;        // 16128
constexpr int TOTAL = D * HW;       // 774144
constexpr int DCHUNK = 4;
constexpr int NDC    = D / DCHUNK;  // 12
constexpr int NXCD   = 8;
constexpr int BAND   = HW / NXCD;   // 2016

// main: 64-thread blocks
constexpr int WPB64  = 16;                                  // wids per 64-thr block
constexpr int MAIN_BLOCKS = NXCD * ((BAND * NDC) / WPB64);  // 12096

// prep grid: transpose + 1 rt block
constexpr int TRANS_BLOCKS = NVIEW * HW / 256; // 252
constexpr int PREP_BLOCKS  = TRANS_BLOCKS + 1;

// ws layout
constexpr size_t FEAH_BYTES = (size_t)NVIEW * HW * C * 2;   // 4,128,768
constexpr size_t RT_OFF     = ((FEAH_BYTES + 255) / 256) * 256;
constexpr size_t WS_NEED    = RT_OFF + 256;

#if __has_builtin(__builtin_amdgcn_fdot2)
__device__ inline float dot2f(h2 a, h2 b, float c) {
    return __builtin_amdgcn_fdot2(a, b, c, false);
}
#else
__device__ inline float dot2f(h2 a, h2 b, float c) {
    return fmaf((float)a.x, (float)b.x, fmaf((float)a.y, (float)b.y, c));
}
#endif

__device__ inline h2 u2h(uint v)  { union { uint u; h2 h; } x; x.u = v; return x.h; }
__device__ inline uint h2u(h2 v)  { union { uint u; h2 h; } x; x.h = v; return x.u; }

// readfirstlane for float: BITCAST, not value-convert
__device__ inline float rfl_f32(float v) {
    union { float f; int i; } u;
    u.f = v;
    u.i = __builtin_amdgcn_readfirstlane(u.i);
    return u.f;
}

// ---------- fast rt: exploits P = [[M t],[0 1]] structure ----------
__device__ inline void fold_Mt(const float* pm, double M[9], double t[3]) {
    const float* E = pm;        // extrinsic
    const float* K = pm + 16;   // intrinsic
    for (int i = 0; i < 3; ++i) {
        for (int j = 0; j < 3; ++j) {
            double s = 0.0;
            for (int k = 0; k < 3; ++k) s += (double)K[i*4+k] * (double)E[k*4+j];
            M[i*3+j] = s;
        }
        double s = 0.0;
        for (int k = 0; k < 3; ++k) s += (double)K[i*4+k] * (double)E[k*4+3];
        t[i] = s;
    }
}

__device__ inline void inv3(const double M[9], double out[9]) {
    const double c00 =  (M[4]*M[8] - M[5]*M[7]);
    const double c01 = -(M[3]*M[8] - M[5]*M[6]);
    const double c02 =  (M[3]*M[7] - M[4]*M[6]);
    const double det = M[0]*c00 + M[1]*c01 + M[2]*c02;
    const double id = 1.0 / det;
    out[0] = c00 * id;
    out[3] = c01 * id;
    out[6] = c02 * id;
    out[1] = -(M[1]*M[8] - M[2]*M[7]) * id;
    out[4] =  (M[0]*M[8] - M[2]*M[6]) * id;
    out[7] = -(M[0]*M[7] - M[1]*M[6]) * id;
    out[2] =  (M[1]*M[5] - M[2]*M[4]) * id;
    out[5] = -(M[0]*M[5] - M[2]*M[3]) * id;
    out[8] =  (M[0]*M[4] - M[1]*M[3]) * id;
}

__device__ inline void compute_rt_fast(const float* proj, float* dst) {
    double Mr[9], tr[3], Mrinv[9];
    fold_Mt(proj, Mr, tr);
    inv3(Mr, Mrinv);
    for (int v = 1; v < NVIEW; ++v) {
        double Ms[9], ts[3];
        fold_Mt(proj + v*32, Ms, ts);
        float* o = dst + (v-1)*12;
        double rot[9];
        for (int i = 0; i < 3; ++i)
            for (int j = 0; j < 3; ++j) {
                double s = 0.0;
                for (int k = 0; k < 3; ++k) s += Ms[i*3+k] * Mrinv[k*3+j];
                rot[i*3+j] = s;
                o[i*3+j] = (float)s;
            }
        for (int i = 0; i < 3; ++i) {
            double s = ts[i];
            for (int k = 0; k < 3; ++k) s -= rot[i*3+k] * tr[k];
            o[9+i] = (float)s;
        }
    }
}

// ---------- kernel 1: transpose CHW fp32 -> HWC fp16 (+1 rt block) ----------
__global__ __launch_bounds__(256) void prep_kernel(
    const float* __restrict__ fea,     // (NVIEW, C, HW) fp32
    const float* __restrict__ proj,    // (NVIEW, 2, 4, 4)
    _Float16* __restrict__ feaH,       // (NVIEW, HW, C) fp16
    float* __restrict__ rtws)          // 36 floats
{
    const int b = blockIdx.x;
    if (b < TRANS_BLOCKS) {
        const int t = b * 256 + threadIdx.x;  // v*HW + p
        const int v = t / HW;
        const int p = t - v * HW;
        const float* src = fea + (size_t)v*C*HW + p;
        h8v ov[4];
        #pragma unroll
        for (int q = 0; q < 4; ++q) {
            #pragma unroll
            for (int k = 0; k < 8; ++k) ov[q][k] = (_Float16)src[(q*8+k)*HW];
        }
        h8v* dst = (h8v*)(feaH + (size_t)t * C);
        #pragma unroll
        for (int q = 0; q < 4; ++q) dst[q] = ov[q];
    } else {
        if (threadIdx.x == 0) compute_rt_fast(proj, rtws);
    }
}

// ---------- kernel 2: main (per-lane full precompute, shfl distribution) ----------
__global__ __launch_bounds__(64, 4) void gwc_main(
    const _Float16* __restrict__ feaH,   // (NVIEW, HW, C) fp16
    const float* __restrict__ rtg,       // 36 floats (ws)
    const float* __restrict__ depth,     // (D, HW)
    float* __restrict__ out)             // (G=8, D, HW)
{
    const int b    = blockIdx.x;
    const int xcd  = b % NXCD;
    const int j    = b / NXCD;                      // 0..1511
    const int tid  = threadIdx.x;
    const int wloc = j * WPB64 + (tid >> 2);
    const int l    = tid & 3;                       // channel octet AND depth-lane
    const int ploc = wloc % BAND;
    const int dc   = wloc / BAND;
    const int p    = xcd * BAND + ploc;
    const int pd0  = dc * DCHUNK * HW + p;

    // rt into SGPRs (uniform, bitcast readfirstlane)
    float srt[36];
    #pragma unroll
    for (int k = 0; k < 36; ++k)
        srt[k] = rfl_f32(rtg[k]);

    // ref features: 16B (8 channels) for this lane
    h2 refq[4];
    {
        const h2* rp = (const h2*)(feaH + (size_t)p*C + l*8);
        refq[0] = rp[0]; refq[1] = rp[1]; refq[2] = rp[2]; refq[3] = rp[3];
    }

    // ---- lane-parallel FULL precompute for depth dd = l ----
    // per view: 4 final element offsets (r+x)*C and 2 packed fp16 weights
    const float fx = (float)(p % W);
    const float fy = (float)(p / W);
    const float dep = depth[pd0 + l*HW];

    int  off[3][4];
    uint wpk[3][2];
    #pragma unroll
    for (int v = 0; v < 3; ++v) {
        const float* rt = srt + v*12;
        const float X = fmaf(fmaf(rt[0], fx, fmaf(rt[1], fy, rt[2])), dep, rt[9]);
        const float Y = fmaf(fmaf(rt[3], fx, fmaf(rt[4], fy, rt[5])), dep, rt[10]);
        const float Z = fmaf(fmaf(rt[6], fx, fmaf(rt[7], fy, rt[8])), dep, rt[11]);
        const float iZ = __builtin_amdgcn_rcpf(Z);
        const float px = X * iZ;
        const float py = Y * iZ;

        const float x0f = floorf(px), y0f = floorf(py);
        const float dx = px - x0f, dy = py - y0f;
        const int x0 = (int)x0f, y0 = (int)y0f;
        const int x1 = x0 + 1,  y1 = y0 + 1;

        const bool vx0 = (x0 >= 0) & (x0 < W);
        const bool vx1 = (x1 >= 0) & (x1 < W);
        const bool vy0 = (y0 >= 0) & (y0 < H);
        const bool vy1 = (y1 >= 0) & (y1 < H);

        const float omx = 1.f - dx, omy = 1.f - dy;
        float w00 = omx*omy, w10 = dx*omy, w01 = omx*dy, w11 = dx*dy;
        if (!(vx0 && vy0)) w00 = 0.f;
        if (!(vx1 && vy0)) w10 = 0.f;
        if (!(vx0 && vy1)) w01 = 0.f;
        if (!(vx1 && vy1)) w11 = 0.f;

        const int xc0 = min(max(x0, 0), W-1), xc1 = min(max(x1, 0), W-1);
        const int yc0 = min(max(y0, 0), H-1), yc1 = min(max(y1, 0), H-1);
        const int r0 = yc0 * W, r1 = yc1 * W;

        off[v][0] = (r0 + xc0) * C;
        off[v][1] = (r0 + xc1) * C;
        off[v][2] = (r1 + xc0) * C;
        off[v][3] = (r1 + xc1) * C;

        h2 wa; wa.x = (_Float16)w00; wa.y = (_Float16)w10;
        h2 wb; wb.x = (_Float16)w01; wb.y = (_Float16)w11;
        wpk[v][0] = h2u(wa);
        wpk[v][1] = h2u(wb);
    }

    const int base = tid & ~3;   // cluster base lane
    const int lo8  = l * 8;      // channel-octet element offset
    const float scale = 1.f / 12.f;

    #pragma unroll
    for (int dd = 0; dd < DCHUNK; ++dd) {
        float accA = 0.f, accB = 0.f;
        #pragma unroll
        for (int v = 0; v < 3; ++v) {
            const int o00 = __shfl(off[v][0], base + dd) + lo8;
            const int o10 = __shfl(off[v][1], base + dd) + lo8;
            const int o01 = __shfl(off[v][2], base + dd) + lo8;
            const int o11 = __shfl(off[v][3], base + dd) + lo8;
            const h2 wa = u2h((uint)__shfl((int)wpk[v][0], base + dd));
            const h2 wb = u2h((uint)__shfl((int)wpk[v][1], base + dd));

            const _Float16* bv = feaH + (size_t)(v+1)*HW*C;
            const h2x4 t00 = *(const h2x4*)(bv + o00);
            const h2x4 t10 = *(const h2x4*)(bv + o10);
            const h2x4 t01 = *(const h2x4*)(bv + o01);
            const h2x4 t11 = *(const h2x4*)(bv + o11);

            h2 w00s; w00s.x = wa.x; w00s.y = wa.x;
            h2 w10s; w10s.x = wa.y; w10s.y = wa.y;
            h2 w01s; w01s.x = wb.x; w01s.y = wb.x;
            h2 w11s; w11s.x = wb.y; w11s.y = wb.y;

            h2 s0 = w00s*t00.x + w10s*t10.x + w01s*t01.x + w11s*t11.x;
            h2 s1 = w00s*t00.y + w10s*t10.y + w01s*t01.y + w11s*t11.y;
            h2 s2 = w00s*t00.z + w10s*t10.z + w01s*t01.z + w11s*t11.z;
            h2 s3 = w00s*t00.w + w10s*t10.w + w01s*t01.w + w11s*t11.w;

            accA = dot2f(s0, refq[0], accA);
            accA = dot2f(s1, refq[1], accA);
            accB = dot2f(s2, refq[2], accB);
            accB = dot2f(s3, refq[3], accB);
        }
        const int pdi = pd0 + dd*HW;
        __builtin_nontemporal_store(accA * scale, &out[(2*l  )*TOTAL + pdi]);
        __builtin_nontemporal_store(accB * scale, &out[(2*l+1)*TOTAL + pdi]);
    }
}

// ---------- last-resort fallback (monolithic fp32, self-contained) ----------
__global__ __launch_bounds__(256) void gwc_fallback(
    const float* __restrict__ fea,
    const float* __restrict__ proj,
    const float* __restrict__ depth,
    float* __restrict__ out)
{
    __shared__ float s_rt[36];
    if (threadIdx.x == 0) compute_rt_fast(proj, s_rt);
    __syncthreads();

    const int tid = blockIdx.x * blockDim.x + threadIdx.x;
    const int p   = tid % HW;
    const float dep = depth[tid];
    const float fx = (float)(p % W);
    const float fy = (float)(p / W);

    float refv[C];
    #pragma unroll
    for (int c = 0; c < C; ++c) refv[c] = fea[c*HW + p];

    float acc[8];
    #pragma unroll
    for (int g = 0; g < 8; ++g) acc[g] = 0.f;

    #pragma unroll
    for (int v = 1; v < NVIEW; ++v) {
        const float* rt = s_rt + (v-1)*12;
        const float X = fmaf(fmaf(rt[0], fx, fmaf(rt[1], fy, rt[2])), dep, rt[9]);
        const float Y = fmaf(fmaf(rt[3], fx, fmaf(rt[4], fy, rt[5])), dep, rt[10]);
        const float Z = fmaf(fmaf(rt[6], fx, fmaf(rt[7], fy, rt[8])), dep, rt[11]);
        const float px = X / Z, py = Y / Z;
        const float x0f = floorf(px), y0f = floorf(py);
        const float dx = px - x0f, dy = py - y0f;
        const int x0 = (int)x0f, y0 = (int)y0f;
        const int x1 = x0 + 1,  y1 = y0 + 1;
        float w00 = (1.f-dx)*(1.f-dy), w10 = dx*(1.f-dy), w01 = (1.f-dx)*dy, w11 = dx*dy;
        const bool vx0 = (x0 >= 0) & (x0 < W), vx1 = (x1 >= 0) & (x1 < W);
        const bool vy0 = (y0 >= 0) & (y0 < H), vy1 = (y1 >= 0) & (y1 < H);
        if (!(vx0 && vy0)) w00 = 0.f;
        if (!(vx1 && vy0)) w10 = 0.f;
        if (!(vx0 && vy1)) w01 = 0.f;
        if (!(vx1 && vy1)) w11 = 0.f;
        const int xc0 = min(max(x0, 0), W-1), xc1 = min(max(x1, 0), W-1);
        const int yc0 = min(max(y0, 0), H-1), yc1 = min(max(y1, 0), H-1);
        const int o00 = yc0*W + xc0, o10 = yc0*W + xc1;
        const int o01 = yc1*W + xc0, o11 = yc1*W + xc1;
        const float* Fv = fea + v*(C*HW);
        #pragma unroll
        for (int c = 0; c < C; ++c) {
            const float* Fc = Fv + c*HW;
            const float s = w00*Fc[o00] + w10*Fc[o10] + w01*Fc[o01] + w11*Fc[o11];
            acc[c >> 2] = fmaf(s, refv[c], acc[c >> 2]);
        }
    }
    const float scale = 1.f / 12.f;
    #pragma unroll
    for (int g = 0; g < 8; ++g)
        out[g*TOTAL + tid] = acc[g] * scale;
}

extern "C" void kernel_launch(void* const* d_in, const int* in_sizes, int n_in,
                              void* d_out, int out_size, void* d_ws, size_t ws_size,
                              hipStream_t stream) {
    const float* fea   = (const float*)d_in[0];
    const float* proj  = (const float*)d_in[1];
    const float* depth = (const float*)d_in[2];
    float* out = (float*)d_out;
    char* ws = (char*)d_ws;

    if (ws_size >= WS_NEED) {
        _Float16* feaH = (_Float16*)ws;
        float*    rtw  = (float*)(ws + RT_OFF);
        prep_kernel<<<PREP_BLOCKS, 256, 0, stream>>>(fea, proj, feaH, rtw);
        gwc_main<<<MAIN_BLOCKS, 64, 0, stream>>>(feaH, rtw, depth, out);
    } else {
        gwc_fallback<<<TOTAL/256, 256, 0, stream>>>(fea, proj, depth, out);
    }
}